// Round 14
// baseline (345.819 us; speedup 1.0000x reference)
//
#include <hip/hip_runtime.h>

// FixSetLinearAttention: B=8 T=2048 C=768 NH=12 hs=64 Lmin=16, 255 segments + tail.
// R14: veins was barrier-lockstep-stalled at 24% occupancy (768 blocks = 3/CU, only
// 3 waves/SIMD; per-iter 1106cy vs 465 ideal). Now 512 threads/block (8 waves x 32
// rows): same LDS/L2 traffic, 6 waves/SIMD -> stalls overlap across blocks.
// Weight casts merged into one launch. Rest identical to R13 (312us, absmax 0.125).

typedef float  f32x4  __attribute__((ext_vector_type(4)));
typedef _Float16 half8 __attribute__((ext_vector_type(8)));
typedef _Float16 half4 __attribute__((ext_vector_type(4)));

#define DEV __device__ __forceinline__
#define MFMA16(a, b, c) __builtin_amdgcn_mfma_f32_16x16x32_f16((a), (b), (c), 0, 0, 0)
#define GLOAD16(gp, lp)                                                  \
  __builtin_amdgcn_global_load_lds(                                      \
      (const __attribute__((address_space(1))) unsigned int*)(gp),       \
      (__attribute__((address_space(3))) unsigned int*)(lp), 16, 0, 0)

// ---------------- prep: f32 -> fp16 ----------------
__global__ __launch_bounds__(256) void k_cast16(const float* __restrict__ in,
                                                _Float16* __restrict__ outh, int n4) {
  int i = blockIdx.x * 256 + threadIdx.x;
  if (i >= n4) return;
  f32x4 v = ((const f32x4*)in)[i];
  half4 o;
#pragma unroll
  for (int c = 0; c < 4; ++c) o[c] = (_Float16)v[c];
  ((half4*)outh)[i] = o;
}

// merged weight casts: Wqkv (442368 x4) + Wv (65536 x4) + Wproj (147456 x4)
__global__ __launch_bounds__(256) void k_castw(const float* __restrict__ Wqkv,
                                               const float* __restrict__ Wv,
                                               const float* __restrict__ Wproj,
                                               _Float16* __restrict__ wq,
                                               _Float16* __restrict__ wv,
                                               _Float16* __restrict__ wp) {
  int i = blockIdx.x * 256 + threadIdx.x;
  const float* src;
  _Float16* dst;
  int idx = i;
  if (idx < 442368) { src = Wqkv; dst = wq; }
  else if (idx < 442368 + 65536) { src = Wv; dst = wv; idx -= 442368; }
  else if (idx < 442368 + 65536 + 147456) { src = Wproj; dst = wp; idx -= 442368 + 65536; }
  else return;
  f32x4 v = ((const f32x4*)src)[idx];
  half4 o;
#pragma unroll
  for (int c = 0; c < 4; ++c) o[c] = (_Float16)v[c];
  ((half4*)dst)[idx] = o;
}

// ---------------- qkv GEMM: C = A @ B^T, fp16, XCD-chunked 1D grid ----------------
__global__ __launch_bounds__(256, 3) void k_gemm_qkv(
    const _Float16* __restrict__ A16, const _Float16* __restrict__ B16,
    _Float16* __restrict__ qo, _Float16* __restrict__ ko, _Float16* __restrict__ v0o) {
  __shared__ _Float16 sA[128][64], sB[128][64];
  const int K = 768;
  int tid = threadIdx.x, lane = tid & 63, wave = tid >> 6;
  int l15 = lane & 15, g = lane >> 4;
  int wr = wave >> 1, wc = wave & 1;
  int wg = (blockIdx.x & 7) * 288 + (blockIdx.x >> 3);
  int n0 = (wg % 18) * 128, m0 = (wg / 18) * 128;
  f32x4 acc[4][4];
#pragma unroll
  for (int a = 0; a < 4; ++a)
#pragma unroll
    for (int b = 0; b < 4; ++b) acc[a][b] = f32x4{0.f, 0.f, 0.f, 0.f};
  int rsel = lane >> 3;
  int csel = (lane & 7) ^ rsel;
  for (int k0 = 0; k0 < K; k0 += 64) {
#pragma unroll
    for (int r = 0; r < 4; ++r) {
      int row = wave * 32 + r * 8 + rsel;
      GLOAD16(&A16[(size_t)(m0 + row) * K + k0 + csel * 8], &sA[wave * 32 + r * 8][0]);
      GLOAD16(&B16[(size_t)(n0 + row) * K + k0 + csel * 8], &sB[wave * 32 + r * 8][0]);
    }
    __syncthreads();
#pragma unroll
    for (int kk = 0; kk < 2; ++kk) {
      int kc = kk * 4 + g;
      int cc = ((kc ^ (l15 & 7)) << 3);
      half8 af[4], bf[4];
#pragma unroll
      for (int mf = 0; mf < 4; ++mf) af[mf] = *(const half8*)&sA[wr * 64 + mf * 16 + l15][cc];
#pragma unroll
      for (int nf = 0; nf < 4; ++nf) bf[nf] = *(const half8*)&sB[wc * 64 + nf * 16 + l15][cc];
#pragma unroll
      for (int mf = 0; mf < 4; ++mf)
#pragma unroll
        for (int nf = 0; nf < 4; ++nf)
          acc[mf][nf] = MFMA16(af[mf], bf[nf], acc[mf][nf]);
    }
    __syncthreads();
  }
  int sec = n0 / 768;
  int nb = n0 - sec * 768;
#pragma unroll
  for (int mf = 0; mf < 4; ++mf)
#pragma unroll
    for (int nf = 0; nf < 4; ++nf)
#pragma unroll
      for (int r = 0; r < 4; ++r) {
        int m = m0 + wr * 64 + mf * 16 + (g << 2) + r;
        int n = nb + wc * 64 + nf * 16 + l15;
        int b = m >> 11, t = m & 2047;
        int h = n >> 6, d = n & 63;
        size_t idx = (((size_t)b * 12 + h) * 2048 + t) * 64 + d;
        _Float16 val = (_Float16)acc[mf][nf][r];
        if (sec == 0) qo[idx] = val;
        else if (sec == 1) ko[idx] = val;
        else v0o[idx] = val;
      }
}

// ---------------- v = (k (x) v0) @ Wv^T + bv  (fp16, 8 waves x 32 rows) ----------------
__global__ __launch_bounds__(512, 6) void k_veins(
    const _Float16* __restrict__ kh, const _Float16* __restrict__ v0g,
    const _Float16* __restrict__ Wvh, const float* __restrict__ bv,
    _Float16* __restrict__ vout) {
  __shared__ _Float16 ks[256][72];     // 36 KB
  __shared__ _Float16 sB[2][64][64];   // 16 KB -> 52 KB total, 3 blocks/CU
  int tid = threadIdx.x, lane = tid & 63, wave = tid >> 6;  // 8 waves
  int l15 = lane & 15, g = lane >> 4, g8 = g << 3;
  size_t row0 = (size_t)blockIdx.x * 256;

  // stage B tile: 8 waves x 1KB (8 e-rows each); linear dest + pre-swizzled source
  auto STAGE = [&](int b, int i) {
    GLOAD16(&Wvh[(size_t)(wave * 8 + (lane >> 3)) * 4096 + i * 64 +
                 (((lane & 7) ^ ((lane >> 3) & 7)) << 3)],
            ((_Float16*)sB) + (size_t)b * 4096 + wave * 8 * 64);
  };

  // stage k tile: 512 threads x 4 half8
#pragma unroll
  for (int r = 0; r < 4; ++r) {
    int row = (tid >> 3) + r * 64;
    int c8 = (tid & 7) << 3;
    *(half8*)&ks[row][c8] = *(const half8*)&kh[(row0 + row) * 64 + c8];
  }
  // v0 fragments resident in regs: [mf][kk], mf<2 (32 rows/wave)
  half8 v0r[2][2];
#pragma unroll
  for (int mf = 0; mf < 2; ++mf) {
    size_t rb = (row0 + wave * 32 + mf * 16 + l15) * 64;
#pragma unroll
    for (int kk = 0; kk < 2; ++kk)
      v0r[mf][kk] = *(const half8*)&v0g[rb + kk * 32 + g8];
  }
  f32x4 acc[2][4];
#pragma unroll
  for (int a = 0; a < 2; ++a)
#pragma unroll
    for (int b = 0; b < 4; ++b) acc[a][b] = f32x4{0.f, 0.f, 0.f, 0.f};

  STAGE(0, 0);
  __syncthreads();
  int r0 = wave * 32 + l15;
  for (int i8 = 0; i8 < 8; ++i8) {
    half8 kr0 = *(const half8*)&ks[r0][i8 * 8];
    half8 kr1 = *(const half8*)&ks[r0 + 16][i8 * 8];
#pragma unroll
    for (int ii = 0; ii < 8; ++ii) {
      int i = i8 * 8 + ii;
      int cur = i & 1;
      if (i < 63) STAGE(cur ^ 1, i + 1);
      half8 b0[4], b1[4];
#pragma unroll
      for (int nf = 0; nf < 4; ++nf) {
        b0[nf] = *(const half8*)&sB[cur][nf * 16 + l15][((g ^ (l15 & 7)) << 3)];
        b1[nf] = *(const half8*)&sB[cur][nf * 16 + l15][(((4 + g) ^ (l15 & 7)) << 3)];
      }
      _Float16 kv0 = kr0[ii], kv1 = kr1[ii];
      {
        half8 a0 = v0r[0][0] * kv0, a1 = v0r[1][0] * kv1;
#pragma unroll
        for (int nf = 0; nf < 4; ++nf) {
          acc[0][nf] = MFMA16(a0, b0[nf], acc[0][nf]);
          acc[1][nf] = MFMA16(a1, b0[nf], acc[1][nf]);
        }
      }
      {
        half8 a0 = v0r[0][1] * kv0, a1 = v0r[1][1] * kv1;
#pragma unroll
        for (int nf = 0; nf < 4; ++nf) {
          acc[0][nf] = MFMA16(a0, b1[nf], acc[0][nf]);
          acc[1][nf] = MFMA16(a1, b1[nf], acc[1][nf]);
        }
      }
      __syncthreads();
    }
  }
#pragma unroll
  for (int mf = 0; mf < 2; ++mf)
#pragma unroll
    for (int nf = 0; nf < 4; ++nf) {
      int e = (nf << 4) + l15;
      float bve = bv[e];
#pragma unroll
      for (int r = 0; r < 4; ++r) {
        int row = wave * 32 + mf * 16 + (g << 2) + r;
        vout[(row0 + row) * 64 + e] = (_Float16)(acc[mf][nf][r] + bve);
      }
    }
}

// ---------------- segment sums -> Ks fp16 [bh][256][64], Vt fp16 [bh][64][256] ----------------
__global__ __launch_bounds__(256) void k_segments(
    const _Float16* __restrict__ kmat, const _Float16* __restrict__ vmat,
    _Float16* __restrict__ Ks, _Float16* __restrict__ Vt) {
  __shared__ float Ls[255][64];
  int bh = blockIdx.x, tid = threadIdx.x;
  size_t bh2048 = (size_t)bh * 2048;
  // ---- K ----
  for (int task = tid; task < 8192; task += 256) {
    int seg = task >> 6, d = task & 63;
    const _Float16* p = kmat + (bh2048 + seg * 16) * 64 + d;
    float s = 0.f;
#pragma unroll
    for (int u = 0; u < 16; ++u) s += (float)p[u * 64];
    Ls[seg][d] = s;
  }
  __syncthreads();
  {
    int bprev = 0, bcur = 128, cnt = 64;
    for (int lev = 1; lev < 8; ++lev) {
      for (int task = tid; task < cnt * 64; task += 256) {
        int i = task >> 6, d = task & 63;
        Ls[bcur + i][d] = Ls[bprev + 2 * i][d] + Ls[bprev + 2 * i + 1][d];
      }
      __syncthreads();
      bprev = bcur; bcur += cnt; cnt >>= 1;
    }
  }
  for (int task = tid; task < 16384; task += 256) {
    int seg = task >> 6;
    float v = (seg < 255) ? Ls[seg][task & 63] : 0.f;
    Ks[(size_t)bh * 16384 + task] = (_Float16)v;
  }
  __syncthreads();
  // ---- V ----
  for (int task = tid; task < 8192; task += 256) {
    int seg = task >> 6, d = task & 63;
    const _Float16* p = vmat + (bh2048 + seg * 16) * 64 + d;
    float s = 0.f;
#pragma unroll
    for (int u = 0; u < 16; ++u) s += (float)p[u * 64];
    Ls[seg][d] = s;
  }
  __syncthreads();
  {
    int bprev = 0, bcur = 128, cnt = 64;
    for (int lev = 1; lev < 8; ++lev) {
      for (int task = tid; task < cnt * 64; task += 256) {
        int i = task >> 6, d = task & 63;
        Ls[bcur + i][d] = Ls[bprev + 2 * i][d] + Ls[bprev + 2 * i + 1][d];
      }
      __syncthreads();
      bprev = bcur; bcur += cnt; cnt >>= 1;
    }
  }
  for (int task = tid; task < 16384; task += 256) {
    int d = task >> 8, seg = task & 255;
    float v = (seg < 255) ? Ls[seg][d] : 0.f;
    Vt[(size_t)bh * 16384 + task] = (_Float16)v;
  }
}

// ---------------- tail prefixes -> tKg [bh][blk][t][d], tVt [bh][blk][e][t16] ----------------
__global__ __launch_bounds__(256) void k_tails(
    const _Float16* __restrict__ km, const _Float16* __restrict__ vm,
    _Float16* __restrict__ tKg, _Float16* __restrict__ tVt) {
  int bh = blockIdx.x >> 3, seg16 = (blockIdx.x & 7) * 16;
  int wave = threadIdx.x >> 6, lane = threadIdx.x & 63;
  for (int task = wave; task < 32; task += 4) {
    int blk = seg16 + (task >> 1);
    size_t base = ((size_t)bh * 2048 + blk * 16) * 64 + lane;
    if (!(task & 1)) {  // K prefix, [t][d] layout
      float ka = 0.f;
      _Float16* o = tKg + (((size_t)bh * 128 + blk) * 16) * 64 + lane;
#pragma unroll
      for (int t = 0; t < 16; ++t) {
        ka += (float)km[base + t * 64];
        o[t * 64] = (_Float16)ka;
      }
    } else {            // V prefix, [e][t] layout
      float va = 0.f;
      half8 lo = {}, hi = {};
#pragma unroll
      for (int t = 0; t < 8; ++t) {
        va += (float)vm[base + t * 64];
        lo[t] = (_Float16)va;
      }
#pragma unroll
      for (int t = 0; t < 8; ++t) {
        va += (float)vm[base + (t + 8) * 64];
        hi[t] = (_Float16)va;
      }
      _Float16* o = tVt + (((size_t)bh * 128 + blk) * 64 + lane) * 16;
      ((half8*)o)[0] = lo;
      ((half8*)o)[1] = hi;
    }
  }
}

// ---------------- MFMA attention (fp16): DMA-staged Ks/Vt chunks, 3 blocks/CU ----------------
__global__ __launch_bounds__(256, 3) void k_attn2(
    const _Float16* __restrict__ qm,
    const _Float16* __restrict__ tKg, const _Float16* __restrict__ tVt,
    const _Float16* __restrict__ Ks, const _Float16* __restrict__ Vt,
    _Float16* __restrict__ outp) {
  __shared__ __align__(16) _Float16 P[4][16][280];     // 35840 B
  __shared__ __align__(16) _Float16 sKs[2][32][64];    //  8192 B
  __shared__ __align__(16) _Float16 sVt[2][64][32];    //  8192 B  -> 52224 total
  int tid = threadIdx.x, lane = tid & 63, wave = tid >> 6;
  int orig = blockIdx.y * 32 + blockIdx.x;
  int wg = (orig & 7) * 384 + (orig >> 3);
  int tile = wg & 31, bh = wg >> 5;
  int t0 = tile * 64, tw0 = t0 + wave * 16;
  int blkw = tile * 4 + wave;
  size_t bh2048 = (size_t)bh * 2048;
  int l15 = lane & 15, g = lane >> 4, g8 = g << 3;

  const _Float16* KsB = Ks + (size_t)bh * 16384;
  const _Float16* VB = Vt + (size_t)bh * 16384;

  auto STAGE_K = [&](int buf, int c) {
    GLOAD16(KsB + (size_t)(c * 32 + wave * 8 + (lane >> 3)) * 64 +
                (((lane & 7) ^ ((lane >> 3) & 7)) << 3),
            &sKs[buf][wave * 8][0]);
  };
  auto STAGE_VT = [&](int buf, int c) {
    GLOAD16(VB + (size_t)(wave * 16 + (lane >> 2)) * 256 + c * 32 +
                (((lane & 3) ^ ((lane >> 2) & 3)) << 3),
            &sVt[buf][wave * 16][0]);
  };

  half8 qf0, qf1, t0f, t1f;
  {
    const _Float16* qp = qm + (bh2048 + tw0 + l15) * 64 + g8;
    qf0 = *(const half8*)qp;
    qf1 = *(const half8*)(qp + 32);
    const _Float16* tp = tKg + (((size_t)bh * 128 + blkw) * 16 + l15) * 64 + g8;
    t0f = *(const half8*)tp;
    t1f = *(const half8*)(tp + 32);
  }
  STAGE_K(0, 0);

  unsigned mA = 0, mE = 0;
#pragma unroll
  for (int nf = 0; nf < 16; ++nf) {
    int seg = nf * 16 + l15;
    if (seg < 255) {
      int m = 256 - seg;
      int cl = 32 - __clz(m - 1);
      int lev = 8 - cl;
      int rdx = (seg - (256 - (256 >> lev)) + 1) * (16 << lev) - 1;
      if (rdx < tw0) mA |= 1u << nf;
      else if (rdx == tw0 + 15) mE |= 1u << nf;
    }
  }

  f32x4 acc[17];
#pragma unroll
  for (int i = 0; i < 17; ++i) acc[i] = f32x4{0.f, 0.f, 0.f, 0.f};

  // ---- QK^T over 8 staged chunks ----
  __syncthreads();
#pragma unroll
  for (int c = 0; c < 8; ++c) {
    if (c < 7) STAGE_K((c + 1) & 1, c + 1);
    int bs = c & 1;
#pragma unroll
    for (int p = 0; p < 2; ++p) {
      int row = p * 16 + l15;
      half8 b0 = *(const half8*)&sKs[bs][row][(g ^ (l15 & 7)) << 3];
      half8 b1 = *(const half8*)&sKs[bs][row][((g + 4) ^ (l15 & 7)) << 3];
      acc[2 * c + p] = MFMA16(qf0, b0, acc[2 * c + p]);
      acc[2 * c + p] = MFMA16(qf1, b1, acc[2 * c + p]);
    }
    __syncthreads();
  }
  acc[16] = MFMA16(qf0, t0f, acc[16]);
  acc[16] = MFMA16(qf1, t1f, acc[16]);

  STAGE_VT(0, 0);
  STAGE_VT(1, 1);

  // ---- softmax (f32, exp2 domain, deferred normalization) ----
  const float c2 = 0.125f * 1.44269504f;
  float mx[4], sm[4], et[4];
#pragma unroll
  for (int r = 0; r < 4; ++r) {
    int tr = g * 4 + r;
    mx[r] = (l15 == tr) ? acc[16][r] * c2 : -3.0e38f;
  }
#pragma unroll
  for (int nf = 0; nf < 16; ++nf) {
    bool bA = (mA >> nf) & 1, bE = (mE >> nf) & 1;
#pragma unroll
    for (int r = 0; r < 4; ++r) {
      bool u = bA || (bE && g == 3 && r == 3);
      if (u) mx[r] = fmaxf(mx[r], acc[nf][r] * c2);
    }
  }
#pragma unroll
  for (int off = 1; off < 16; off <<= 1)
#pragma unroll
    for (int r = 0; r < 4; ++r) mx[r] = fmaxf(mx[r], __shfl_xor(mx[r], off));
#pragma unroll
  for (int r = 0; r < 4; ++r) {
    int tr = g * 4 + r;
    et[r] = (l15 == tr) ? exp2f(acc[16][r] * c2 - mx[r]) : 0.f;
    sm[r] = et[r];
  }
#pragma unroll
  for (int nf = 0; nf < 16; ++nf) {
    bool bA = (mA >> nf) & 1, bE = (mE >> nf) & 1;
#pragma unroll
    for (int r = 0; r < 4; ++r) {
      bool u = bA || (bE && g == 3 && r == 3);
      float e = u ? exp2f(acc[nf][r] * c2 - mx[r]) : 0.f;
      acc[nf][r] = e;
      sm[r] += e;
    }
  }
#pragma unroll
  for (int off = 1; off < 16; off <<= 1)
#pragma unroll
    for (int r = 0; r < 4; ++r) sm[r] += __shfl_xor(sm[r], off);
  float inv[4];
#pragma unroll
  for (int r = 0; r < 4; ++r) inv[r] = 1.f / sm[r];

  // ---- P writes (raw exp values; normalization deferred) ----
  {
    half4 z4 = {};
    *(half4*)&P[wave][lane >> 2][256 + (lane & 3) * 4] = z4;
  }
#pragma unroll
  for (int nf = 0; nf < 16; ++nf)
#pragma unroll
    for (int r = 0; r < 4; ++r)
      P[wave][g * 4 + r][nf * 16 + l15] = (_Float16)acc[nf][r];
#pragma unroll
  for (int r = 0; r < 4; ++r)
    if (l15 == g * 4 + r) P[wave][l15][256 + l15] = (_Float16)et[r];

  // ---- PV over 8 staged chunks ----
  f32x4 oa[4];
#pragma unroll
  for (int i = 0; i < 4; ++i) oa[i] = f32x4{0.f, 0.f, 0.f, 0.f};
  __syncthreads();
#pragma unroll
  for (int c = 0; c < 8; ++c) {
    int bs = c & 1;
    half8 pa = *(const half8*)&P[wave][l15][c * 32 + g8];
#pragma unroll
    for (int n2 = 0; n2 < 4; ++n2) {
      half8 vb = *(const half8*)&sVt[bs][n2 * 16 + l15][(g ^ (l15 & 3)) << 3];
      oa[n2] = MFMA16(pa, vb, oa[n2]);
    }
    __syncthreads();
    if (c < 6) STAGE_VT(bs, c + 2);
  }
  {  // tail k-step
    half8 pa = *(const half8*)&P[wave][l15][256 + (g & 1) * 8];
    const _Float16* tvb = tVt + ((size_t)bh * 128 + blkw) * 1024;
#pragma unroll
    for (int n2 = 0; n2 < 4; ++n2) {
      half8 vt = {};
      if (g < 2)
        vt = *(const half8*)(tvb + (size_t)(n2 * 16 + l15) * 16 + g8);
      oa[n2] = MFMA16(pa, vt, oa[n2]);
    }
  }
  // ---- output (normalize here) ----
  int b = bh / 12, h = bh - b * 12;
  size_t obase = ((size_t)b * 2048 + tw0) * 768 + h * 64;
#pragma unroll
  for (int n2 = 0; n2 < 4; ++n2)
#pragma unroll
    for (int r = 0; r < 4; ++r)
      outp[obase + (size_t)(g * 4 + r) * 768 + n2 * 16 + l15] = (_Float16)(oa[n2][r] * inv[r]);
}

// ---------------- proj GEMM: d_out = out_pre @ Wproj^T (fp16, XCD-chunked) ----------------
__global__ __launch_bounds__(256, 3) void k_gemm_proj(
    const _Float16* __restrict__ A16, const _Float16* __restrict__ B16,
    float* __restrict__ C) {
  __shared__ _Float16 sA[128][64], sB[128][64];
  const int K = 768;
  int tid = threadIdx.x, lane = tid & 63, wave = tid >> 6;
  int l15 = lane & 15, g = lane >> 4;
  int wr = wave >> 1, wc = wave & 1;
  int wg = (blockIdx.x & 7) * 96 + (blockIdx.x >> 3);
  int n0 = (wg % 6) * 128, m0 = (wg / 6) * 128;
  f32x4 acc[4][4];
#pragma unroll
  for (int a = 0; a < 4; ++a)
#pragma unroll
    for (int b = 0; b < 4; ++b) acc[a][b] = f32x4{0.f, 0.f, 0.f, 0.f};
  int rsel = lane >> 3;
  int csel = (lane & 7) ^ rsel;
  for (int k0 = 0; k0 < K; k0 += 64) {
#pragma unroll
    for (int r = 0; r < 4; ++r) {
      int row = wave * 32 + r * 8 + rsel;
      GLOAD16(&A16[(size_t)(m0 + row) * K + k0 + csel * 8], &sA[wave * 32 + r * 8][0]);
      GLOAD16(&B16[(size_t)(n0 + row) * K + k0 + csel * 8], &sB[wave * 32 + r * 8][0]);
    }
    __syncthreads();
#pragma unroll
    for (int kk = 0; kk < 2; ++kk) {
      int kc = kk * 4 + g;
      int cc = ((kc ^ (l15 & 7)) << 3);
      half8 af[4], bf[4];
#pragma unroll
      for (int mf = 0; mf < 4; ++mf) af[mf] = *(const half8*)&sA[wr * 64 + mf * 16 + l15][cc];
#pragma unroll
      for (int nf = 0; nf < 4; ++nf) bf[nf] = *(const half8*)&sB[wc * 64 + nf * 16 + l15][cc];
#pragma unroll
      for (int mf = 0; mf < 4; ++mf)
#pragma unroll
        for (int nf = 0; nf < 4; ++nf)
          acc[mf][nf] = MFMA16(af[mf], bf[nf], acc[mf][nf]);
    }
    __syncthreads();
  }
#pragma unroll
  for (int mf = 0; mf < 4; ++mf)
#pragma unroll
    for (int nf = 0; nf < 4; ++nf)
#pragma unroll
      for (int r = 0; r < 4; ++r) {
        int m = m0 + wr * 64 + mf * 16 + (g << 2) + r;
        int n = n0 + wc * 64 + nf * 16 + l15;
        C[(size_t)m * 768 + n] = acc[mf][nf][r];
      }
}

// ---------------- host launch ----------------
extern "C" void kernel_launch(void* const* d_in, const int* in_sizes, int n_in,
                              void* d_out, int out_size, void* d_ws, size_t ws_size,
                              hipStream_t stream) {
  const float* x = (const float*)d_in[0];
  const float* Wqkv = (const float*)d_in[1];
  const float* Wproj = (const float*)d_in[2];
  const float* Wv = (const float*)d_in[3];
  const float* bv = (const float*)d_in[4];
  float* out = (float*)d_out;
  char* ws = (char*)d_ws;
  size_t off = 0;
  auto alloc = [&](size_t bytes) -> void* {
    void* p = (void*)(ws + off);
    off += (bytes + 255) & ~(size_t)255;
    return p;
  };
  _Float16* x16  = (_Float16*)alloc(12582912ull * 2);
  _Float16* wq16 = (_Float16*)alloc(1769472ull * 2);
  _Float16* wv16 = (_Float16*)alloc(262144ull * 2 + 8192);
  _Float16* wp16 = (_Float16*)alloc(589824ull * 2);
  _Float16* q16  = (_Float16*)alloc(12582912ull * 2);
  _Float16* k16  = (_Float16*)alloc(12582912ull * 2);
  _Float16* v016 = (_Float16*)alloc(12582912ull * 2);
  _Float16* vm16 = (_Float16*)alloc(12582912ull * 2);
  _Float16* Ks   = (_Float16*)alloc(1572864ull * 2);
  _Float16* Vt   = (_Float16*)alloc(1572864ull * 2);
  _Float16* tKg  = (_Float16*)alloc(12582912ull * 2);
  _Float16* tVt  = (_Float16*)alloc(12582912ull * 2);
  _Float16* outp = (_Float16*)alloc(12582912ull * 2);

  k_cast16<<<dim3(12288), dim3(256), 0, stream>>>(x, x16, 3145728);
  k_castw<<<dim3(2560), dim3(256), 0, stream>>>(Wqkv, Wv, Wproj, wq16, wv16, wp16);
  k_gemm_qkv<<<dim3(2304), dim3(256), 0, stream>>>(x16, wq16, q16, k16, v016);
  k_veins<<<dim3(768), dim3(512), 0, stream>>>(k16, v016, wv16, bv, vm16);
  k_segments<<<dim3(96), dim3(256), 0, stream>>>(k16, vm16, Ks, Vt);
  k_tails<<<dim3(768), dim3(256), 0, stream>>>(k16, vm16, tKg, tVt);
  k_attn2<<<dim3(32, 96), dim3(256), 0, stream>>>(q16, tKg, tVt, Ks, Vt, outp);
  k_gemm_proj<<<dim3(768), dim3(256), 0, stream>>>(outp, wp16, out);
}

// Round 15
// 318.500 us; speedup vs baseline: 1.0858x; 1.0858x over previous
//
#include <hip/hip_runtime.h>

// FixSetLinearAttention: B=8 T=2048 C=768 NH=12 hs=64 Lmin=16, 255 segments + tail.
// R15 = R14 with veins __launch_bounds__(512,4). R14's (512,6) capped VGPR at ~85
// (demand ~80 -> allocator chose 40 + spill, WRITE 113MB). (512,4) -> 128-reg cap,
// 2 blocks/CU x 8 waves = 16 waves/CU (vs R13's 12), no spill.

typedef float  f32x4  __attribute__((ext_vector_type(4)));
typedef _Float16 half8 __attribute__((ext_vector_type(8)));
typedef _Float16 half4 __attribute__((ext_vector_type(4)));

#define DEV __device__ __forceinline__
#define MFMA16(a, b, c) __builtin_amdgcn_mfma_f32_16x16x32_f16((a), (b), (c), 0, 0, 0)
#define GLOAD16(gp, lp)                                                  \
  __builtin_amdgcn_global_load_lds(                                      \
      (const __attribute__((address_space(1))) unsigned int*)(gp),       \
      (__attribute__((address_space(3))) unsigned int*)(lp), 16, 0, 0)

// ---------------- prep: f32 -> fp16 ----------------
__global__ __launch_bounds__(256) void k_cast16(const float* __restrict__ in,
                                                _Float16* __restrict__ outh, int n4) {
  int i = blockIdx.x * 256 + threadIdx.x;
  if (i >= n4) return;
  f32x4 v = ((const f32x4*)in)[i];
  half4 o;
#pragma unroll
  for (int c = 0; c < 4; ++c) o[c] = (_Float16)v[c];
  ((half4*)outh)[i] = o;
}

// merged weight casts: Wqkv (442368 x4) + Wv (65536 x4) + Wproj (147456 x4)
__global__ __launch_bounds__(256) void k_castw(const float* __restrict__ Wqkv,
                                               const float* __restrict__ Wv,
                                               const float* __restrict__ Wproj,
                                               _Float16* __restrict__ wq,
                                               _Float16* __restrict__ wv,
                                               _Float16* __restrict__ wp) {
  int i = blockIdx.x * 256 + threadIdx.x;
  const float* src;
  _Float16* dst;
  int idx = i;
  if (idx < 442368) { src = Wqkv; dst = wq; }
  else if (idx < 442368 + 65536) { src = Wv; dst = wv; idx -= 442368; }
  else if (idx < 442368 + 65536 + 147456) { src = Wproj; dst = wp; idx -= 442368 + 65536; }
  else return;
  f32x4 v = ((const f32x4*)src)[idx];
  half4 o;
#pragma unroll
  for (int c = 0; c < 4; ++c) o[c] = (_Float16)v[c];
  ((half4*)dst)[idx] = o;
}

// ---------------- qkv GEMM: C = A @ B^T, fp16, XCD-chunked 1D grid ----------------
__global__ __launch_bounds__(256, 3) void k_gemm_qkv(
    const _Float16* __restrict__ A16, const _Float16* __restrict__ B16,
    _Float16* __restrict__ qo, _Float16* __restrict__ ko, _Float16* __restrict__ v0o) {
  __shared__ _Float16 sA[128][64], sB[128][64];
  const int K = 768;
  int tid = threadIdx.x, lane = tid & 63, wave = tid >> 6;
  int l15 = lane & 15, g = lane >> 4;
  int wr = wave >> 1, wc = wave & 1;
  int wg = (blockIdx.x & 7) * 288 + (blockIdx.x >> 3);
  int n0 = (wg % 18) * 128, m0 = (wg / 18) * 128;
  f32x4 acc[4][4];
#pragma unroll
  for (int a = 0; a < 4; ++a)
#pragma unroll
    for (int b = 0; b < 4; ++b) acc[a][b] = f32x4{0.f, 0.f, 0.f, 0.f};
  int rsel = lane >> 3;
  int csel = (lane & 7) ^ rsel;
  for (int k0 = 0; k0 < K; k0 += 64) {
#pragma unroll
    for (int r = 0; r < 4; ++r) {
      int row = wave * 32 + r * 8 + rsel;
      GLOAD16(&A16[(size_t)(m0 + row) * K + k0 + csel * 8], &sA[wave * 32 + r * 8][0]);
      GLOAD16(&B16[(size_t)(n0 + row) * K + k0 + csel * 8], &sB[wave * 32 + r * 8][0]);
    }
    __syncthreads();
#pragma unroll
    for (int kk = 0; kk < 2; ++kk) {
      int kc = kk * 4 + g;
      int cc = ((kc ^ (l15 & 7)) << 3);
      half8 af[4], bf[4];
#pragma unroll
      for (int mf = 0; mf < 4; ++mf) af[mf] = *(const half8*)&sA[wr * 64 + mf * 16 + l15][cc];
#pragma unroll
      for (int nf = 0; nf < 4; ++nf) bf[nf] = *(const half8*)&sB[wc * 64 + nf * 16 + l15][cc];
#pragma unroll
      for (int mf = 0; mf < 4; ++mf)
#pragma unroll
        for (int nf = 0; nf < 4; ++nf)
          acc[mf][nf] = MFMA16(af[mf], bf[nf], acc[mf][nf]);
    }
    __syncthreads();
  }
  int sec = n0 / 768;
  int nb = n0 - sec * 768;
#pragma unroll
  for (int mf = 0; mf < 4; ++mf)
#pragma unroll
    for (int nf = 0; nf < 4; ++nf)
#pragma unroll
      for (int r = 0; r < 4; ++r) {
        int m = m0 + wr * 64 + mf * 16 + (g << 2) + r;
        int n = nb + wc * 64 + nf * 16 + l15;
        int b = m >> 11, t = m & 2047;
        int h = n >> 6, d = n & 63;
        size_t idx = (((size_t)b * 12 + h) * 2048 + t) * 64 + d;
        _Float16 val = (_Float16)acc[mf][nf][r];
        if (sec == 0) qo[idx] = val;
        else if (sec == 1) ko[idx] = val;
        else v0o[idx] = val;
      }
}

// ---------------- v = (k (x) v0) @ Wv^T + bv  (fp16, 8 waves x 32 rows) ----------------
__global__ __launch_bounds__(512, 4) void k_veins(
    const _Float16* __restrict__ kh, const _Float16* __restrict__ v0g,
    const _Float16* __restrict__ Wvh, const float* __restrict__ bv,
    _Float16* __restrict__ vout) {
  __shared__ _Float16 ks[256][72];     // 36 KB
  __shared__ _Float16 sB[2][64][64];   // 16 KB -> 52 KB total
  int tid = threadIdx.x, lane = tid & 63, wave = tid >> 6;  // 8 waves
  int l15 = lane & 15, g = lane >> 4, g8 = g << 3;
  size_t row0 = (size_t)blockIdx.x * 256;

  auto STAGE = [&](int b, int i) {
    GLOAD16(&Wvh[(size_t)(wave * 8 + (lane >> 3)) * 4096 + i * 64 +
                 (((lane & 7) ^ ((lane >> 3) & 7)) << 3)],
            ((_Float16*)sB) + (size_t)b * 4096 + wave * 8 * 64);
  };

#pragma unroll
  for (int r = 0; r < 4; ++r) {
    int row = (tid >> 3) + r * 64;
    int c8 = (tid & 7) << 3;
    *(half8*)&ks[row][c8] = *(const half8*)&kh[(row0 + row) * 64 + c8];
  }
  half8 v0r[2][2];
#pragma unroll
  for (int mf = 0; mf < 2; ++mf) {
    size_t rb = (row0 + wave * 32 + mf * 16 + l15) * 64;
#pragma unroll
    for (int kk = 0; kk < 2; ++kk)
      v0r[mf][kk] = *(const half8*)&v0g[rb + kk * 32 + g8];
  }
  f32x4 acc[2][4];
#pragma unroll
  for (int a = 0; a < 2; ++a)
#pragma unroll
    for (int b = 0; b < 4; ++b) acc[a][b] = f32x4{0.f, 0.f, 0.f, 0.f};

  STAGE(0, 0);
  __syncthreads();
  int r0 = wave * 32 + l15;
  for (int i8 = 0; i8 < 8; ++i8) {
    half8 kr0 = *(const half8*)&ks[r0][i8 * 8];
    half8 kr1 = *(const half8*)&ks[r0 + 16][i8 * 8];
#pragma unroll
    for (int ii = 0; ii < 8; ++ii) {
      int i = i8 * 8 + ii;
      int cur = i & 1;
      if (i < 63) STAGE(cur ^ 1, i + 1);
      half8 b0[4], b1[4];
#pragma unroll
      for (int nf = 0; nf < 4; ++nf) {
        b0[nf] = *(const half8*)&sB[cur][nf * 16 + l15][((g ^ (l15 & 7)) << 3)];
        b1[nf] = *(const half8*)&sB[cur][nf * 16 + l15][(((4 + g) ^ (l15 & 7)) << 3)];
      }
      _Float16 kv0 = kr0[ii], kv1 = kr1[ii];
      {
        half8 a0 = v0r[0][0] * kv0, a1 = v0r[1][0] * kv1;
#pragma unroll
        for (int nf = 0; nf < 4; ++nf) {
          acc[0][nf] = MFMA16(a0, b0[nf], acc[0][nf]);
          acc[1][nf] = MFMA16(a1, b0[nf], acc[1][nf]);
        }
      }
      {
        half8 a0 = v0r[0][1] * kv0, a1 = v0r[1][1] * kv1;
#pragma unroll
        for (int nf = 0; nf < 4; ++nf) {
          acc[0][nf] = MFMA16(a0, b1[nf], acc[0][nf]);
          acc[1][nf] = MFMA16(a1, b1[nf], acc[1][nf]);
        }
      }
      __syncthreads();
    }
  }
#pragma unroll
  for (int mf = 0; mf < 2; ++mf)
#pragma unroll
    for (int nf = 0; nf < 4; ++nf) {
      int e = (nf << 4) + l15;
      float bve = bv[e];
#pragma unroll
      for (int r = 0; r < 4; ++r) {
        int row = wave * 32 + mf * 16 + (g << 2) + r;
        vout[(row0 + row) * 64 + e] = (_Float16)(acc[mf][nf][r] + bve);
      }
    }
}

// ---------------- segment sums -> Ks fp16 [bh][256][64], Vt fp16 [bh][64][256] ----------------
__global__ __launch_bounds__(256) void k_segments(
    const _Float16* __restrict__ kmat, const _Float16* __restrict__ vmat,
    _Float16* __restrict__ Ks, _Float16* __restrict__ Vt) {
  __shared__ float Ls[255][64];
  int bh = blockIdx.x, tid = threadIdx.x;
  size_t bh2048 = (size_t)bh * 2048;
  // ---- K ----
  for (int task = tid; task < 8192; task += 256) {
    int seg = task >> 6, d = task & 63;
    const _Float16* p = kmat + (bh2048 + seg * 16) * 64 + d;
    float s = 0.f;
#pragma unroll
    for (int u = 0; u < 16; ++u) s += (float)p[u * 64];
    Ls[seg][d] = s;
  }
  __syncthreads();
  {
    int bprev = 0, bcur = 128, cnt = 64;
    for (int lev = 1; lev < 8; ++lev) {
      for (int task = tid; task < cnt * 64; task += 256) {
        int i = task >> 6, d = task & 63;
        Ls[bcur + i][d] = Ls[bprev + 2 * i][d] + Ls[bprev + 2 * i + 1][d];
      }
      __syncthreads();
      bprev = bcur; bcur += cnt; cnt >>= 1;
    }
  }
  for (int task = tid; task < 16384; task += 256) {
    int seg = task >> 6;
    float v = (seg < 255) ? Ls[seg][task & 63] : 0.f;
    Ks[(size_t)bh * 16384 + task] = (_Float16)v;
  }
  __syncthreads();
  // ---- V ----
  for (int task = tid; task < 8192; task += 256) {
    int seg = task >> 6, d = task & 63;
    const _Float16* p = vmat + (bh2048 + seg * 16) * 64 + d;
    float s = 0.f;
#pragma unroll
    for (int u = 0; u < 16; ++u) s += (float)p[u * 64];
    Ls[seg][d] = s;
  }
  __syncthreads();
  {
    int bprev = 0, bcur = 128, cnt = 64;
    for (int lev = 1; lev < 8; ++lev) {
      for (int task = tid; task < cnt * 64; task += 256) {
        int i = task >> 6, d = task & 63;
        Ls[bcur + i][d] = Ls[bprev + 2 * i][d] + Ls[bprev + 2 * i + 1][d];
      }
      __syncthreads();
      bprev = bcur; bcur += cnt; cnt >>= 1;
    }
  }
  for (int task = tid; task < 16384; task += 256) {
    int d = task >> 8, seg = task & 255;
    float v = (seg < 255) ? Ls[seg][d] : 0.f;
    Vt[(size_t)bh * 16384 + task] = (_Float16)v;
  }
}

// ---------------- tail prefixes -> tKg [bh][blk][t][d], tVt [bh][blk][e][t16] ----------------
__global__ __launch_bounds__(256) void k_tails(
    const _Float16* __restrict__ km, const _Float16* __restrict__ vm,
    _Float16* __restrict__ tKg, _Float16* __restrict__ tVt) {
  int bh = blockIdx.x >> 3, seg16 = (blockIdx.x & 7) * 16;
  int wave = threadIdx.x >> 6, lane = threadIdx.x & 63;
  for (int task = wave; task < 32; task += 4) {
    int blk = seg16 + (task >> 1);
    size_t base = ((size_t)bh * 2048 + blk * 16) * 64 + lane;
    if (!(task & 1)) {  // K prefix, [t][d] layout
      float ka = 0.f;
      _Float16* o = tKg + (((size_t)bh * 128 + blk) * 16) * 64 + lane;
#pragma unroll
      for (int t = 0; t < 16; ++t) {
        ka += (float)km[base + t * 64];
        o[t * 64] = (_Float16)ka;
      }
    } else {            // V prefix, [e][t] layout
      float va = 0.f;
      half8 lo = {}, hi = {};
#pragma unroll
      for (int t = 0; t < 8; ++t) {
        va += (float)vm[base + t * 64];
        lo[t] = (_Float16)va;
      }
#pragma unroll
      for (int t = 0; t < 8; ++t) {
        va += (float)vm[base + (t + 8) * 64];
        hi[t] = (_Float16)va;
      }
      _Float16* o = tVt + (((size_t)bh * 128 + blk) * 64 + lane) * 16;
      ((half8*)o)[0] = lo;
      ((half8*)o)[1] = hi;
    }
  }
}

// ---------------- MFMA attention (fp16): DMA-staged Ks/Vt chunks, 3 blocks/CU ----------------
__global__ __launch_bounds__(256, 3) void k_attn2(
    const _Float16* __restrict__ qm,
    const _Float16* __restrict__ tKg, const _Float16* __restrict__ tVt,
    const _Float16* __restrict__ Ks, const _Float16* __restrict__ Vt,
    _Float16* __restrict__ outp) {
  __shared__ __align__(16) _Float16 P[4][16][280];     // 35840 B
  __shared__ __align__(16) _Float16 sKs[2][32][64];    //  8192 B
  __shared__ __align__(16) _Float16 sVt[2][64][32];    //  8192 B  -> 52224 total
  int tid = threadIdx.x, lane = tid & 63, wave = tid >> 6;
  int orig = blockIdx.y * 32 + blockIdx.x;
  int wg = (orig & 7) * 384 + (orig >> 3);
  int tile = wg & 31, bh = wg >> 5;
  int t0 = tile * 64, tw0 = t0 + wave * 16;
  int blkw = tile * 4 + wave;
  size_t bh2048 = (size_t)bh * 2048;
  int l15 = lane & 15, g = lane >> 4, g8 = g << 3;

  const _Float16* KsB = Ks + (size_t)bh * 16384;
  const _Float16* VB = Vt + (size_t)bh * 16384;

  auto STAGE_K = [&](int buf, int c) {
    GLOAD16(KsB + (size_t)(c * 32 + wave * 8 + (lane >> 3)) * 64 +
                (((lane & 7) ^ ((lane >> 3) & 7)) << 3),
            &sKs[buf][wave * 8][0]);
  };
  auto STAGE_VT = [&](int buf, int c) {
    GLOAD16(VB + (size_t)(wave * 16 + (lane >> 2)) * 256 + c * 32 +
                (((lane & 3) ^ ((lane >> 2) & 3)) << 3),
            &sVt[buf][wave * 16][0]);
  };

  half8 qf0, qf1, t0f, t1f;
  {
    const _Float16* qp = qm + (bh2048 + tw0 + l15) * 64 + g8;
    qf0 = *(const half8*)qp;
    qf1 = *(const half8*)(qp + 32);
    const _Float16* tp = tKg + (((size_t)bh * 128 + blkw) * 16 + l15) * 64 + g8;
    t0f = *(const half8*)tp;
    t1f = *(const half8*)(tp + 32);
  }
  STAGE_K(0, 0);

  unsigned mA = 0, mE = 0;
#pragma unroll
  for (int nf = 0; nf < 16; ++nf) {
    int seg = nf * 16 + l15;
    if (seg < 255) {
      int m = 256 - seg;
      int cl = 32 - __clz(m - 1);
      int lev = 8 - cl;
      int rdx = (seg - (256 - (256 >> lev)) + 1) * (16 << lev) - 1;
      if (rdx < tw0) mA |= 1u << nf;
      else if (rdx == tw0 + 15) mE |= 1u << nf;
    }
  }

  f32x4 acc[17];
#pragma unroll
  for (int i = 0; i < 17; ++i) acc[i] = f32x4{0.f, 0.f, 0.f, 0.f};

  // ---- QK^T over 8 staged chunks ----
  __syncthreads();
#pragma unroll
  for (int c = 0; c < 8; ++c) {
    if (c < 7) STAGE_K((c + 1) & 1, c + 1);
    int bs = c & 1;
#pragma unroll
    for (int p = 0; p < 2; ++p) {
      int row = p * 16 + l15;
      half8 b0 = *(const half8*)&sKs[bs][row][(g ^ (l15 & 7)) << 3];
      half8 b1 = *(const half8*)&sKs[bs][row][((g + 4) ^ (l15 & 7)) << 3];
      acc[2 * c + p] = MFMA16(qf0, b0, acc[2 * c + p]);
      acc[2 * c + p] = MFMA16(qf1, b1, acc[2 * c + p]);
    }
    __syncthreads();
  }
  acc[16] = MFMA16(qf0, t0f, acc[16]);
  acc[16] = MFMA16(qf1, t1f, acc[16]);

  STAGE_VT(0, 0);
  STAGE_VT(1, 1);

  // ---- softmax (f32, exp2 domain, deferred normalization) ----
  const float c2 = 0.125f * 1.44269504f;
  float mx[4], sm[4], et[4];
#pragma unroll
  for (int r = 0; r < 4; ++r) {
    int tr = g * 4 + r;
    mx[r] = (l15 == tr) ? acc[16][r] * c2 : -3.0e38f;
  }
#pragma unroll
  for (int nf = 0; nf < 16; ++nf) {
    bool bA = (mA >> nf) & 1, bE = (mE >> nf) & 1;
#pragma unroll
    for (int r = 0; r < 4; ++r) {
      bool u = bA || (bE && g == 3 && r == 3);
      if (u) mx[r] = fmaxf(mx[r], acc[nf][r] * c2);
    }
  }
#pragma unroll
  for (int off = 1; off < 16; off <<= 1)
#pragma unroll
    for (int r = 0; r < 4; ++r) mx[r] = fmaxf(mx[r], __shfl_xor(mx[r], off));
#pragma unroll
  for (int r = 0; r < 4; ++r) {
    int tr = g * 4 + r;
    et[r] = (l15 == tr) ? exp2f(acc[16][r] * c2 - mx[r]) : 0.f;
    sm[r] = et[r];
  }
#pragma unroll
  for (int nf = 0; nf < 16; ++nf) {
    bool bA = (mA >> nf) & 1, bE = (mE >> nf) & 1;
#pragma unroll
    for (int r = 0; r < 4; ++r) {
      bool u = bA || (bE && g == 3 && r == 3);
      float e = u ? exp2f(acc[nf][r] * c2 - mx[r]) : 0.f;
      acc[nf][r] = e;
      sm[r] += e;
    }
  }
#pragma unroll
  for (int off = 1; off < 16; off <<= 1)
#pragma unroll
    for (int r = 0; r < 4; ++r) sm[r] += __shfl_xor(sm[r], off);
  float inv[4];
#pragma unroll
  for (int r = 0; r < 4; ++r) inv[r] = 1.f / sm[r];

  // ---- P writes (raw exp values; normalization deferred) ----
  {
    half4 z4 = {};
    *(half4*)&P[wave][lane >> 2][256 + (lane & 3) * 4] = z4;
  }
#pragma unroll
  for (int nf = 0; nf < 16; ++nf)
#pragma unroll
    for (int r = 0; r < 4; ++r)
      P[wave][g * 4 + r][nf * 16 + l15] = (_Float16)acc[nf][r];
#pragma unroll
  for (int r = 0; r < 4; ++r)
    if (l15 == g * 4 + r) P[wave][l15][256 + l15] = (_Float16)et[r];

  // ---- PV over 8 staged chunks ----
  f32x4 oa[4];
#pragma unroll
  for (int i = 0; i < 4; ++i) oa[i] = f32x4{0.f, 0.f, 0.f, 0.f};
  __syncthreads();
#pragma unroll
  for (int c = 0; c < 8; ++c) {
    int bs = c & 1;
    half8 pa = *(const half8*)&P[wave][l15][c * 32 + g8];
#pragma unroll
    for (int n2 = 0; n2 < 4; ++n2) {
      half8 vb = *(const half8*)&sVt[bs][n2 * 16 + l15][(g ^ (l15 & 3)) << 3];
      oa[n2] = MFMA16(pa, vb, oa[n2]);
    }
    __syncthreads();
    if (c < 6) STAGE_VT(bs, c + 2);
  }
  {  // tail k-step
    half8 pa = *(const half8*)&P[wave][l15][256 + (g & 1) * 8];
    const _Float16* tvb = tVt + ((size_t)bh * 128 + blkw) * 1024;
#pragma unroll
    for (int n2 = 0; n2 < 4; ++n2) {
      half8 vt = {};
      if (g < 2)
        vt = *(const half8*)(tvb + (size_t)(n2 * 16 + l15) * 16 + g8);
      oa[n2] = MFMA16(pa, vt, oa[n2]);
    }
  }
  // ---- output (normalize here) ----
  int b = bh / 12, h = bh - b * 12;
  size_t obase = ((size_t)b * 2048 + tw0) * 768 + h * 64;
#pragma unroll
  for (int n2 = 0; n2 < 4; ++n2)
#pragma unroll
    for (int r = 0; r < 4; ++r)
      outp[obase + (size_t)(g * 4 + r) * 768 + n2 * 16 + l15] = (_Float16)(oa[n2][r] * inv[r]);
}

// ---------------- proj GEMM: d_out = out_pre @ Wproj^T (fp16, XCD-chunked) ----------------
__global__ __launch_bounds__(256, 3) void k_gemm_proj(
    const _Float16* __restrict__ A16, const _Float16* __restrict__ B16,
    float* __restrict__ C) {
  __shared__ _Float16 sA[128][64], sB[128][64];
  const int K = 768;
  int tid = threadIdx.x, lane = tid & 63, wave = tid >> 6;
  int l15 = lane & 15, g = lane >> 4;
  int wr = wave >> 1, wc = wave & 1;
  int wg = (blockIdx.x & 7) * 96 + (blockIdx.x >> 3);
  int n0 = (wg % 6) * 128, m0 = (wg / 6) * 128;
  f32x4 acc[4][4];
#pragma unroll
  for (int a = 0; a < 4; ++a)
#pragma unroll
    for (int b = 0; b < 4; ++b) acc[a][b] = f32x4{0.f, 0.f, 0.f, 0.f};
  int rsel = lane >> 3;
  int csel = (lane & 7) ^ rsel;
  for (int k0 = 0; k0 < K; k0 += 64) {
#pragma unroll
    for (int r = 0; r < 4; ++r) {
      int row = wave * 32 + r * 8 + rsel;
      GLOAD16(&A16[(size_t)(m0 + row) * K + k0 + csel * 8], &sA[wave * 32 + r * 8][0]);
      GLOAD16(&B16[(size_t)(n0 + row) * K + k0 + csel * 8], &sB[wave * 32 + r * 8][0]);
    }
    __syncthreads();
#pragma unroll
    for (int kk = 0; kk < 2; ++kk) {
      int kc = kk * 4 + g;
      int cc = ((kc ^ (l15 & 7)) << 3);
      half8 af[4], bf[4];
#pragma unroll
      for (int mf = 0; mf < 4; ++mf) af[mf] = *(const half8*)&sA[wr * 64 + mf * 16 + l15][cc];
#pragma unroll
      for (int nf = 0; nf < 4; ++nf) bf[nf] = *(const half8*)&sB[wc * 64 + nf * 16 + l15][cc];
#pragma unroll
      for (int mf = 0; mf < 4; ++mf)
#pragma unroll
        for (int nf = 0; nf < 4; ++nf)
          acc[mf][nf] = MFMA16(af[mf], bf[nf], acc[mf][nf]);
    }
    __syncthreads();
  }
#pragma unroll
  for (int mf = 0; mf < 4; ++mf)
#pragma unroll
    for (int nf = 0; nf < 4; ++nf)
#pragma unroll
      for (int r = 0; r < 4; ++r) {
        int m = m0 + wr * 64 + mf * 16 + (g << 2) + r;
        int n = n0 + wc * 64 + nf * 16 + l15;
        C[(size_t)m * 768 + n] = acc[mf][nf][r];
      }
}

// ---------------- host launch ----------------
extern "C" void kernel_launch(void* const* d_in, const int* in_sizes, int n_in,
                              void* d_out, int out_size, void* d_ws, size_t ws_size,
                              hipStream_t stream) {
  const float* x = (const float*)d_in[0];
  const float* Wqkv = (const float*)d_in[1];
  const float* Wproj = (const float*)d_in[2];
  const float* Wv = (const float*)d_in[3];
  const float* bv = (const float*)d_in[4];
  float* out = (float*)d_out;
  char* ws = (char*)d_ws;
  size_t off = 0;
  auto alloc = [&](size_t bytes) -> void* {
    void* p = (void*)(ws + off);
    off += (bytes + 255) & ~(size_t)255;
    return p;
  };
  _Float16* x16  = (_Float16*)alloc(12582912ull * 2);
  _Float16* wq16 = (_Float16*)alloc(1769472ull * 2);
  _Float16* wv16 = (_Float16*)alloc(262144ull * 2 + 8192);
  _Float16* wp16 = (_Float16*)alloc(589824ull * 2);
  _Float16* q16  = (_Float16*)alloc(12582912ull * 2);
  _Float16* k16  = (_Float16*)alloc(12582912ull * 2);
  _Float16* v016 = (_Float16*)alloc(12582912ull * 2);
  _Float16* vm16 = (_Float16*)alloc(12582912ull * 2);
  _Float16* Ks   = (_Float16*)alloc(1572864ull * 2);
  _Float16* Vt   = (_Float16*)alloc(1572864ull * 2);
  _Float16* tKg  = (_Float16*)alloc(12582912ull * 2);
  _Float16* tVt  = (_Float16*)alloc(12582912ull * 2);
  _Float16* outp = (_Float16*)alloc(12582912ull * 2);

  k_cast16<<<dim3(12288), dim3(256), 0, stream>>>(x, x16, 3145728);
  k_castw<<<dim3(2560), dim3(256), 0, stream>>>(Wqkv, Wv, Wproj, wq16, wv16, wp16);
  k_gemm_qkv<<<dim3(2304), dim3(256), 0, stream>>>(x16, wq16, q16, k16, v016);
  k_veins<<<dim3(768), dim3(512), 0, stream>>>(k16, v016, wv16, bv, vm16);
  k_segments<<<dim3(96), dim3(256), 0, stream>>>(k16, vm16, Ks, Vt);
  k_tails<<<dim3(768), dim3(256), 0, stream>>>(k16, vm16, tKg, tVt);
  k_attn2<<<dim3(32, 96), dim3(256), 0, stream>>>(q16, tKg, tVt, Ks, Vt, outp);
  k_gemm_proj<<<dim3(768), dim3(256), 0, stream>>>(outp, wp16, out);
}

// Round 16
// 307.351 us; speedup vs baseline: 1.1252x; 1.0363x over previous
//
#include <hip/hip_runtime.h>

// FixSetLinearAttention: B=8 T=2048 C=768 NH=12 hs=64 Lmin=16, 255 segments + tail.
// R16: veins reverted to R13's proven 4-wave (256,3) config (88.5us; R15's 8-wave
// 2-block variant was 97.4 -- fewer independent barrier domains lose). segments/tails
// bh-swizzled so each XCD owns bh [12c,12c+12) in BOTH kernels -> tails L2-hits
// segments' 50MB stream. Merged weight casts kept.

typedef float  f32x4  __attribute__((ext_vector_type(4)));
typedef _Float16 half8 __attribute__((ext_vector_type(8)));
typedef _Float16 half4 __attribute__((ext_vector_type(4)));

#define DEV __device__ __forceinline__
#define MFMA16(a, b, c) __builtin_amdgcn_mfma_f32_16x16x32_f16((a), (b), (c), 0, 0, 0)
#define GLOAD16(gp, lp)                                                  \
  __builtin_amdgcn_global_load_lds(                                      \
      (const __attribute__((address_space(1))) unsigned int*)(gp),       \
      (__attribute__((address_space(3))) unsigned int*)(lp), 16, 0, 0)

// ---------------- prep: f32 -> fp16 ----------------
__global__ __launch_bounds__(256) void k_cast16(const float* __restrict__ in,
                                                _Float16* __restrict__ outh, int n4) {
  int i = blockIdx.x * 256 + threadIdx.x;
  if (i >= n4) return;
  f32x4 v = ((const f32x4*)in)[i];
  half4 o;
#pragma unroll
  for (int c = 0; c < 4; ++c) o[c] = (_Float16)v[c];
  ((half4*)outh)[i] = o;
}

// merged weight casts: Wqkv (442368 x4) + Wv (65536 x4) + Wproj (147456 x4)
__global__ __launch_bounds__(256) void k_castw(const float* __restrict__ Wqkv,
                                               const float* __restrict__ Wv,
                                               const float* __restrict__ Wproj,
                                               _Float16* __restrict__ wq,
                                               _Float16* __restrict__ wv,
                                               _Float16* __restrict__ wp) {
  int i = blockIdx.x * 256 + threadIdx.x;
  const float* src;
  _Float16* dst;
  int idx = i;
  if (idx < 442368) { src = Wqkv; dst = wq; }
  else if (idx < 442368 + 65536) { src = Wv; dst = wv; idx -= 442368; }
  else if (idx < 442368 + 65536 + 147456) { src = Wproj; dst = wp; idx -= 442368 + 65536; }
  else return;
  f32x4 v = ((const f32x4*)src)[idx];
  half4 o;
#pragma unroll
  for (int c = 0; c < 4; ++c) o[c] = (_Float16)v[c];
  ((half4*)dst)[idx] = o;
}

// ---------------- qkv GEMM: C = A @ B^T, fp16, XCD-chunked 1D grid ----------------
__global__ __launch_bounds__(256, 3) void k_gemm_qkv(
    const _Float16* __restrict__ A16, const _Float16* __restrict__ B16,
    _Float16* __restrict__ qo, _Float16* __restrict__ ko, _Float16* __restrict__ v0o) {
  __shared__ _Float16 sA[128][64], sB[128][64];
  const int K = 768;
  int tid = threadIdx.x, lane = tid & 63, wave = tid >> 6;
  int l15 = lane & 15, g = lane >> 4;
  int wr = wave >> 1, wc = wave & 1;
  int wg = (blockIdx.x & 7) * 288 + (blockIdx.x >> 3);
  int n0 = (wg % 18) * 128, m0 = (wg / 18) * 128;
  f32x4 acc[4][4];
#pragma unroll
  for (int a = 0; a < 4; ++a)
#pragma unroll
    for (int b = 0; b < 4; ++b) acc[a][b] = f32x4{0.f, 0.f, 0.f, 0.f};
  int rsel = lane >> 3;
  int csel = (lane & 7) ^ rsel;
  for (int k0 = 0; k0 < K; k0 += 64) {
#pragma unroll
    for (int r = 0; r < 4; ++r) {
      int row = wave * 32 + r * 8 + rsel;
      GLOAD16(&A16[(size_t)(m0 + row) * K + k0 + csel * 8], &sA[wave * 32 + r * 8][0]);
      GLOAD16(&B16[(size_t)(n0 + row) * K + k0 + csel * 8], &sB[wave * 32 + r * 8][0]);
    }
    __syncthreads();
#pragma unroll
    for (int kk = 0; kk < 2; ++kk) {
      int kc = kk * 4 + g;
      int cc = ((kc ^ (l15 & 7)) << 3);
      half8 af[4], bf[4];
#pragma unroll
      for (int mf = 0; mf < 4; ++mf) af[mf] = *(const half8*)&sA[wr * 64 + mf * 16 + l15][cc];
#pragma unroll
      for (int nf = 0; nf < 4; ++nf) bf[nf] = *(const half8*)&sB[wc * 64 + nf * 16 + l15][cc];
#pragma unroll
      for (int mf = 0; mf < 4; ++mf)
#pragma unroll
        for (int nf = 0; nf < 4; ++nf)
          acc[mf][nf] = MFMA16(af[mf], bf[nf], acc[mf][nf]);
    }
    __syncthreads();
  }
  int sec = n0 / 768;
  int nb = n0 - sec * 768;
#pragma unroll
  for (int mf = 0; mf < 4; ++mf)
#pragma unroll
    for (int nf = 0; nf < 4; ++nf)
#pragma unroll
      for (int r = 0; r < 4; ++r) {
        int m = m0 + wr * 64 + mf * 16 + (g << 2) + r;
        int n = nb + wc * 64 + nf * 16 + l15;
        int b = m >> 11, t = m & 2047;
        int h = n >> 6, d = n & 63;
        size_t idx = (((size_t)b * 12 + h) * 2048 + t) * 64 + d;
        _Float16 val = (_Float16)acc[mf][nf][r];
        if (sec == 0) qo[idx] = val;
        else if (sec == 1) ko[idx] = val;
        else v0o[idx] = val;
      }
}

// ---------------- v = (k (x) v0) @ Wv^T + bv  (fp16, LDS-shared B tiles, R13) ----------------
__global__ __launch_bounds__(256, 3) void k_veins(
    const _Float16* __restrict__ kh, const _Float16* __restrict__ v0g,
    const _Float16* __restrict__ Wvh, const float* __restrict__ bv,
    _Float16* __restrict__ vout) {
  __shared__ _Float16 ks[256][72];
  __shared__ _Float16 sB[2][64][64];
  int tid = threadIdx.x, lane = tid & 63, wave = tid >> 6;
  int l15 = lane & 15, g = lane >> 4, g8 = g << 3;
  size_t row0 = (size_t)blockIdx.x * 256;

  int srow_lo = wave * 8 + (lane >> 3);
  int scsrc = (lane & 7) ^ (lane >> 3);
  auto STAGE = [&](int b, int i) {
#pragma unroll
    for (int h = 0; h < 2; ++h) {
      GLOAD16(&Wvh[(size_t)(h * 32 + srow_lo) * 4096 + i * 64 + (scsrc << 3)],
              ((_Float16*)sB) + (size_t)b * 4096 + (h * 256 + wave * 64) * 8);
    }
  };

#pragma unroll
  for (int r = 0; r < 8; ++r) {
    int row = (tid >> 3) + r * 32;
    int c8 = (tid & 7) << 3;
    *(half8*)&ks[row][c8] = *(const half8*)&kh[(row0 + row) * 64 + c8];
  }
  half8 v0r[4][2];
#pragma unroll
  for (int mf = 0; mf < 4; ++mf) {
    size_t rb = (row0 + wave * 64 + mf * 16 + l15) * 64;
#pragma unroll
    for (int kk = 0; kk < 2; ++kk)
      v0r[mf][kk] = *(const half8*)&v0g[rb + kk * 32 + g8];
  }
  f32x4 acc[4][4];
#pragma unroll
  for (int a = 0; a < 4; ++a)
#pragma unroll
    for (int b = 0; b < 4; ++b) acc[a][b] = f32x4{0.f, 0.f, 0.f, 0.f};

  STAGE(0, 0);
  __syncthreads();
  int r0 = wave * 64 + l15;
  for (int i8 = 0; i8 < 8; ++i8) {
    half8 kr0 = *(const half8*)&ks[r0][i8 * 8];
    half8 kr1 = *(const half8*)&ks[r0 + 16][i8 * 8];
    half8 kr2 = *(const half8*)&ks[r0 + 32][i8 * 8];
    half8 kr3 = *(const half8*)&ks[r0 + 48][i8 * 8];
#pragma unroll
    for (int ii = 0; ii < 8; ++ii) {
      int i = i8 * 8 + ii;
      int cur = i & 1;
      if (i < 63) STAGE(cur ^ 1, i + 1);
      half8 b0[4], b1[4];
#pragma unroll
      for (int nf = 0; nf < 4; ++nf) {
        b0[nf] = *(const half8*)&sB[cur][nf * 16 + l15][((g ^ (l15 & 7)) << 3)];
        b1[nf] = *(const half8*)&sB[cur][nf * 16 + l15][(((4 + g) ^ (l15 & 7)) << 3)];
      }
      _Float16 kv0 = kr0[ii], kv1 = kr1[ii], kv2 = kr2[ii], kv3 = kr3[ii];
      {
        half8 a0 = v0r[0][0] * kv0, a1 = v0r[1][0] * kv1;
        half8 a2 = v0r[2][0] * kv2, a3 = v0r[3][0] * kv3;
#pragma unroll
        for (int nf = 0; nf < 4; ++nf) {
          acc[0][nf] = MFMA16(a0, b0[nf], acc[0][nf]);
          acc[1][nf] = MFMA16(a1, b0[nf], acc[1][nf]);
          acc[2][nf] = MFMA16(a2, b0[nf], acc[2][nf]);
          acc[3][nf] = MFMA16(a3, b0[nf], acc[3][nf]);
        }
      }
      {
        half8 a0 = v0r[0][1] * kv0, a1 = v0r[1][1] * kv1;
        half8 a2 = v0r[2][1] * kv2, a3 = v0r[3][1] * kv3;
#pragma unroll
        for (int nf = 0; nf < 4; ++nf) {
          acc[0][nf] = MFMA16(a0, b1[nf], acc[0][nf]);
          acc[1][nf] = MFMA16(a1, b1[nf], acc[1][nf]);
          acc[2][nf] = MFMA16(a2, b1[nf], acc[2][nf]);
          acc[3][nf] = MFMA16(a3, b1[nf], acc[3][nf]);
        }
      }
      __syncthreads();
    }
  }
#pragma unroll
  for (int mf = 0; mf < 4; ++mf)
#pragma unroll
    for (int nf = 0; nf < 4; ++nf) {
      int e = (nf << 4) + l15;
      float bve = bv[e];
#pragma unroll
      for (int r = 0; r < 4; ++r) {
        int row = wave * 64 + mf * 16 + (g << 2) + r;
        vout[(row0 + row) * 64 + e] = (_Float16)(acc[mf][nf][r] + bve);
      }
    }
}

// ---------------- segment sums (bh XCD-chunked: XCD c owns bh [12c,12c+12)) ----------------
__global__ __launch_bounds__(256) void k_segments(
    const _Float16* __restrict__ kmat, const _Float16* __restrict__ vmat,
    _Float16* __restrict__ Ks, _Float16* __restrict__ Vt) {
  __shared__ float Ls[255][64];
  int s = blockIdx.x;
  int bh = (s & 7) * 12 + (s >> 3);   // 96 blocks, bijective
  int tid = threadIdx.x;
  size_t bh2048 = (size_t)bh * 2048;
  // ---- K ----
  for (int task = tid; task < 8192; task += 256) {
    int seg = task >> 6, d = task & 63;
    const _Float16* p = kmat + (bh2048 + seg * 16) * 64 + d;
    float sm = 0.f;
#pragma unroll
    for (int u = 0; u < 16; ++u) sm += (float)p[u * 64];
    Ls[seg][d] = sm;
  }
  __syncthreads();
  {
    int bprev = 0, bcur = 128, cnt = 64;
    for (int lev = 1; lev < 8; ++lev) {
      for (int task = tid; task < cnt * 64; task += 256) {
        int i = task >> 6, d = task & 63;
        Ls[bcur + i][d] = Ls[bprev + 2 * i][d] + Ls[bprev + 2 * i + 1][d];
      }
      __syncthreads();
      bprev = bcur; bcur += cnt; cnt >>= 1;
    }
  }
  for (int task = tid; task < 16384; task += 256) {
    int seg = task >> 6;
    float v = (seg < 255) ? Ls[seg][task & 63] : 0.f;
    Ks[(size_t)bh * 16384 + task] = (_Float16)v;
  }
  __syncthreads();
  // ---- V ----
  for (int task = tid; task < 8192; task += 256) {
    int seg = task >> 6, d = task & 63;
    const _Float16* p = vmat + (bh2048 + seg * 16) * 64 + d;
    float sm = 0.f;
#pragma unroll
    for (int u = 0; u < 16; ++u) sm += (float)p[u * 64];
    Ls[seg][d] = sm;
  }
  __syncthreads();
  {
    int bprev = 0, bcur = 128, cnt = 64;
    for (int lev = 1; lev < 8; ++lev) {
      for (int task = tid; task < cnt * 64; task += 256) {
        int i = task >> 6, d = task & 63;
        Ls[bcur + i][d] = Ls[bprev + 2 * i][d] + Ls[bprev + 2 * i + 1][d];
      }
      __syncthreads();
      bprev = bcur; bcur += cnt; cnt >>= 1;
    }
  }
  for (int task = tid; task < 16384; task += 256) {
    int d = task >> 8, seg = task & 255;
    float v = (seg < 255) ? Ls[seg][d] : 0.f;
    Vt[(size_t)bh * 16384 + task] = (_Float16)v;
  }
}

// ---------------- tail prefixes (bh XCD-aligned with k_segments) ----------------
__global__ __launch_bounds__(256) void k_tails(
    const _Float16* __restrict__ km, const _Float16* __restrict__ vm,
    _Float16* __restrict__ tKg, _Float16* __restrict__ tVt) {
  int B = blockIdx.x;                       // 768 blocks
  int bh = (B & 7) * 12 + (B >> 6);         // XCD B%8 -> bh chunk [12c,12c+12)
  int seg16 = ((B >> 3) & 7) * 16;          // 8 sub-blocks per bh
  int wave = threadIdx.x >> 6, lane = threadIdx.x & 63;
  for (int task = wave; task < 32; task += 4) {
    int blk = seg16 + (task >> 1);
    size_t base = ((size_t)bh * 2048 + blk * 16) * 64 + lane;
    if (!(task & 1)) {  // K prefix, [t][d] layout
      float ka = 0.f;
      _Float16* o = tKg + (((size_t)bh * 128 + blk) * 16) * 64 + lane;
#pragma unroll
      for (int t = 0; t < 16; ++t) {
        ka += (float)km[base + t * 64];
        o[t * 64] = (_Float16)ka;
      }
    } else {            // V prefix, [e][t] layout
      float va = 0.f;
      half8 lo = {}, hi = {};
#pragma unroll
      for (int t = 0; t < 8; ++t) {
        va += (float)vm[base + t * 64];
        lo[t] = (_Float16)va;
      }
#pragma unroll
      for (int t = 0; t < 8; ++t) {
        va += (float)vm[base + (t + 8) * 64];
        hi[t] = (_Float16)va;
      }
      _Float16* o = tVt + (((size_t)bh * 128 + blk) * 64 + lane) * 16;
      ((half8*)o)[0] = lo;
      ((half8*)o)[1] = hi;
    }
  }
}

// ---------------- MFMA attention (fp16): DMA-staged Ks/Vt chunks, 3 blocks/CU ----------------
__global__ __launch_bounds__(256, 3) void k_attn2(
    const _Float16* __restrict__ qm,
    const _Float16* __restrict__ tKg, const _Float16* __restrict__ tVt,
    const _Float16* __restrict__ Ks, const _Float16* __restrict__ Vt,
    _Float16* __restrict__ outp) {
  __shared__ __align__(16) _Float16 P[4][16][280];     // 35840 B
  __shared__ __align__(16) _Float16 sKs[2][32][64];    //  8192 B
  __shared__ __align__(16) _Float16 sVt[2][64][32];    //  8192 B  -> 52224 total
  int tid = threadIdx.x, lane = tid & 63, wave = tid >> 6;
  int orig = blockIdx.y * 32 + blockIdx.x;
  int wg = (orig & 7) * 384 + (orig >> 3);
  int tile = wg & 31, bh = wg >> 5;
  int t0 = tile * 64, tw0 = t0 + wave * 16;
  int blkw = tile * 4 + wave;
  size_t bh2048 = (size_t)bh * 2048;
  int l15 = lane & 15, g = lane >> 4, g8 = g << 3;

  const _Float16* KsB = Ks + (size_t)bh * 16384;
  const _Float16* VB = Vt + (size_t)bh * 16384;

  auto STAGE_K = [&](int buf, int c) {
    GLOAD16(KsB + (size_t)(c * 32 + wave * 8 + (lane >> 3)) * 64 +
                (((lane & 7) ^ ((lane >> 3) & 7)) << 3),
            &sKs[buf][wave * 8][0]);
  };
  auto STAGE_VT = [&](int buf, int c) {
    GLOAD16(VB + (size_t)(wave * 16 + (lane >> 2)) * 256 + c * 32 +
                (((lane & 3) ^ ((lane >> 2) & 3)) << 3),
            &sVt[buf][wave * 16][0]);
  };

  half8 qf0, qf1, t0f, t1f;
  {
    const _Float16* qp = qm + (bh2048 + tw0 + l15) * 64 + g8;
    qf0 = *(const half8*)qp;
    qf1 = *(const half8*)(qp + 32);
    const _Float16* tp = tKg + (((size_t)bh * 128 + blkw) * 16 + l15) * 64 + g8;
    t0f = *(const half8*)tp;
    t1f = *(const half8*)(tp + 32);
  }
  STAGE_K(0, 0);

  unsigned mA = 0, mE = 0;
#pragma unroll
  for (int nf = 0; nf < 16; ++nf) {
    int seg = nf * 16 + l15;
    if (seg < 255) {
      int m = 256 - seg;
      int cl = 32 - __clz(m - 1);
      int lev = 8 - cl;
      int rdx = (seg - (256 - (256 >> lev)) + 1) * (16 << lev) - 1;
      if (rdx < tw0) mA |= 1u << nf;
      else if (rdx == tw0 + 15) mE |= 1u << nf;
    }
  }

  f32x4 acc[17];
#pragma unroll
  for (int i = 0; i < 17; ++i) acc[i] = f32x4{0.f, 0.f, 0.f, 0.f};

  // ---- QK^T over 8 staged chunks ----
  __syncthreads();
#pragma unroll
  for (int c = 0; c < 8; ++c) {
    if (c < 7) STAGE_K((c + 1) & 1, c + 1);
    int bs = c & 1;
#pragma unroll
    for (int p = 0; p < 2; ++p) {
      int row = p * 16 + l15;
      half8 b0 = *(const half8*)&sKs[bs][row][(g ^ (l15 & 7)) << 3];
      half8 b1 = *(const half8*)&sKs[bs][row][((g + 4) ^ (l15 & 7)) << 3];
      acc[2 * c + p] = MFMA16(qf0, b0, acc[2 * c + p]);
      acc[2 * c + p] = MFMA16(qf1, b1, acc[2 * c + p]);
    }
    __syncthreads();
  }
  acc[16] = MFMA16(qf0, t0f, acc[16]);
  acc[16] = MFMA16(qf1, t1f, acc[16]);

  STAGE_VT(0, 0);
  STAGE_VT(1, 1);

  // ---- softmax (f32, exp2 domain, deferred normalization) ----
  const float c2 = 0.125f * 1.44269504f;
  float mx[4], sm[4], et[4];
#pragma unroll
  for (int r = 0; r < 4; ++r) {
    int tr = g * 4 + r;
    mx[r] = (l15 == tr) ? acc[16][r] * c2 : -3.0e38f;
  }
#pragma unroll
  for (int nf = 0; nf < 16; ++nf) {
    bool bA = (mA >> nf) & 1, bE = (mE >> nf) & 1;
#pragma unroll
    for (int r = 0; r < 4; ++r) {
      bool u = bA || (bE && g == 3 && r == 3);
      if (u) mx[r] = fmaxf(mx[r], acc[nf][r] * c2);
    }
  }
#pragma unroll
  for (int off = 1; off < 16; off <<= 1)
#pragma unroll
    for (int r = 0; r < 4; ++r) mx[r] = fmaxf(mx[r], __shfl_xor(mx[r], off));
#pragma unroll
  for (int r = 0; r < 4; ++r) {
    int tr = g * 4 + r;
    et[r] = (l15 == tr) ? exp2f(acc[16][r] * c2 - mx[r]) : 0.f;
    sm[r] = et[r];
  }
#pragma unroll
  for (int nf = 0; nf < 16; ++nf) {
    bool bA = (mA >> nf) & 1, bE = (mE >> nf) & 1;
#pragma unroll
    for (int r = 0; r < 4; ++r) {
      bool u = bA || (bE && g == 3 && r == 3);
      float e = u ? exp2f(acc[nf][r] * c2 - mx[r]) : 0.f;
      acc[nf][r] = e;
      sm[r] += e;
    }
  }
#pragma unroll
  for (int off = 1; off < 16; off <<= 1)
#pragma unroll
    for (int r = 0; r < 4; ++r) sm[r] += __shfl_xor(sm[r], off);
  float inv[4];
#pragma unroll
  for (int r = 0; r < 4; ++r) inv[r] = 1.f / sm[r];

  // ---- P writes (raw exp values; normalization deferred) ----
  {
    half4 z4 = {};
    *(half4*)&P[wave][lane >> 2][256 + (lane & 3) * 4] = z4;
  }
#pragma unroll
  for (int nf = 0; nf < 16; ++nf)
#pragma unroll
    for (int r = 0; r < 4; ++r)
      P[wave][g * 4 + r][nf * 16 + l15] = (_Float16)acc[nf][r];
#pragma unroll
  for (int r = 0; r < 4; ++r)
    if (l15 == g * 4 + r) P[wave][l15][256 + l15] = (_Float16)et[r];

  // ---- PV over 8 staged chunks ----
  f32x4 oa[4];
#pragma unroll
  for (int i = 0; i < 4; ++i) oa[i] = f32x4{0.f, 0.f, 0.f, 0.f};
  __syncthreads();
#pragma unroll
  for (int c = 0; c < 8; ++c) {
    int bs = c & 1;
    half8 pa = *(const half8*)&P[wave][l15][c * 32 + g8];
#pragma unroll
    for (int n2 = 0; n2 < 4; ++n2) {
      half8 vb = *(const half8*)&sVt[bs][n2 * 16 + l15][(g ^ (l15 & 3)) << 3];
      oa[n2] = MFMA16(pa, vb, oa[n2]);
    }
    __syncthreads();
    if (c < 6) STAGE_VT(bs, c + 2);
  }
  {  // tail k-step
    half8 pa = *(const half8*)&P[wave][l15][256 + (g & 1) * 8];
    const _Float16* tvb = tVt + ((size_t)bh * 128 + blkw) * 1024;
#pragma unroll
    for (int n2 = 0; n2 < 4; ++n2) {
      half8 vt = {};
      if (g < 2)
        vt = *(const half8*)(tvb + (size_t)(n2 * 16 + l15) * 16 + g8);
      oa[n2] = MFMA16(pa, vt, oa[n2]);
    }
  }
  // ---- output (normalize here) ----
  int b = bh / 12, h = bh - b * 12;
  size_t obase = ((size_t)b * 2048 + tw0) * 768 + h * 64;
#pragma unroll
  for (int n2 = 0; n2 < 4; ++n2)
#pragma unroll
    for (int r = 0; r < 4; ++r)
      outp[obase + (size_t)(g * 4 + r) * 768 + n2 * 16 + l15] = (_Float16)(oa[n2][r] * inv[r]);
}

// ---------------- proj GEMM: d_out = out_pre @ Wproj^T (fp16, XCD-chunked) ----------------
__global__ __launch_bounds__(256, 3) void k_gemm_proj(
    const _Float16* __restrict__ A16, const _Float16* __restrict__ B16,
    float* __restrict__ C) {
  __shared__ _Float16 sA[128][64], sB[128][64];
  const int K = 768;
  int tid = threadIdx.x, lane = tid & 63, wave = tid >> 6;
  int l15 = lane & 15, g = lane >> 4;
  int wr = wave >> 1, wc = wave & 1;
  int wg = (blockIdx.x & 7) * 96 + (blockIdx.x >> 3);
  int n0 = (wg % 6) * 128, m0 = (wg / 6) * 128;
  f32x4 acc[4][4];
#pragma unroll
  for (int a = 0; a < 4; ++a)
#pragma unroll
    for (int b = 0; b < 4; ++b) acc[a][b] = f32x4{0.f, 0.f, 0.f, 0.f};
  int rsel = lane >> 3;
  int csel = (lane & 7) ^ rsel;
  for (int k0 = 0; k0 < K; k0 += 64) {
#pragma unroll
    for (int r = 0; r < 4; ++r) {
      int row = wave * 32 + r * 8 + rsel;
      GLOAD16(&A16[(size_t)(m0 + row) * K + k0 + csel * 8], &sA[wave * 32 + r * 8][0]);
      GLOAD16(&B16[(size_t)(n0 + row) * K + k0 + csel * 8], &sB[wave * 32 + r * 8][0]);
    }
    __syncthreads();
#pragma unroll
    for (int kk = 0; kk < 2; ++kk) {
      int kc = kk * 4 + g;
      int cc = ((kc ^ (l15 & 7)) << 3);
      half8 af[4], bf[4];
#pragma unroll
      for (int mf = 0; mf < 4; ++mf) af[mf] = *(const half8*)&sA[wr * 64 + mf * 16 + l15][cc];
#pragma unroll
      for (int nf = 0; nf < 4; ++nf) bf[nf] = *(const half8*)&sB[wc * 64 + nf * 16 + l15][cc];
#pragma unroll
      for (int mf = 0; mf < 4; ++mf)
#pragma unroll
        for (int nf = 0; nf < 4; ++nf)
          acc[mf][nf] = MFMA16(af[mf], bf[nf], acc[mf][nf]);
    }
    __syncthreads();
  }
#pragma unroll
  for (int mf = 0; mf < 4; ++mf)
#pragma unroll
    for (int nf = 0; nf < 4; ++nf)
#pragma unroll
      for (int r = 0; r < 4; ++r) {
        int m = m0 + wr * 64 + mf * 16 + (g << 2) + r;
        int n = n0 + wc * 64 + nf * 16 + l15;
        C[(size_t)m * 768 + n] = acc[mf][nf][r];
      }
}

// ---------------- host launch ----------------
extern "C" void kernel_launch(void* const* d_in, const int* in_sizes, int n_in,
                              void* d_out, int out_size, void* d_ws, size_t ws_size,
                              hipStream_t stream) {
  const float* x = (const float*)d_in[0];
  const float* Wqkv = (const float*)d_in[1];
  const float* Wproj = (const float*)d_in[2];
  const float* Wv = (const float*)d_in[3];
  const float* bv = (const float*)d_in[4];
  float* out = (float*)d_out;
  char* ws = (char*)d_ws;
  size_t off = 0;
  auto alloc = [&](size_t bytes) -> void* {
    void* p = (void*)(ws + off);
    off += (bytes + 255) & ~(size_t)255;
    return p;
  };
  _Float16* x16  = (_Float16*)alloc(12582912ull * 2);
  _Float16* wq16 = (_Float16*)alloc(1769472ull * 2);
  _Float16* wv16 = (_Float16*)alloc(262144ull * 2 + 8192);
  _Float16* wp16 = (_Float16*)alloc(589824ull * 2);
  _Float16* q16  = (_Float16*)alloc(12582912ull * 2);
  _Float16* k16  = (_Float16*)alloc(12582912ull * 2);
  _Float16* v016 = (_Float16*)alloc(12582912ull * 2);
  _Float16* vm16 = (_Float16*)alloc(12582912ull * 2);
  _Float16* Ks   = (_Float16*)alloc(1572864ull * 2);
  _Float16* Vt   = (_Float16*)alloc(1572864ull * 2);
  _Float16* tKg  = (_Float16*)alloc(12582912ull * 2);
  _Float16* tVt  = (_Float16*)alloc(12582912ull * 2);
  _Float16* outp = (_Float16*)alloc(12582912ull * 2);

  k_cast16<<<dim3(12288), dim3(256), 0, stream>>>(x, x16, 3145728);
  k_castw<<<dim3(2560), dim3(256), 0, stream>>>(Wqkv, Wv, Wproj, wq16, wv16, wp16);
  k_gemm_qkv<<<dim3(2304), dim3(256), 0, stream>>>(x16, wq16, q16, k16, v016);
  k_veins<<<dim3(768), dim3(256), 0, stream>>>(k16, v016, wv16, bv, vm16);
  k_segments<<<dim3(96), dim3(256), 0, stream>>>(k16, vm16, Ks, Vt);
  k_tails<<<dim3(768), dim3(256), 0, stream>>>(k16, vm16, tKg, tVt);
  k_attn2<<<dim3(32, 96), dim3(256), 0, stream>>>(q16, tKg, tVt, Ks, Vt, outp);
  k_gemm_proj<<<dim3(768), dim3(256), 0, stream>>>(outp, wp16, out);
}

// Round 17
// 292.105 us; speedup vs baseline: 1.1839x; 1.0522x over previous
//
#include <hip/hip_runtime.h>

// FixSetLinearAttention: B=8 T=2048 C=768 NH=12 hs=64 Lmin=16, 255 segments + tail.
// R17: k_tails now also emits level-0 segment sums (f32, 6MB) -- its t=15 prefix IS
// the 16-token segment sum -- and k_hier (96 blocks) builds the 255-seg hierarchy
// from those 6MB instead of re-reading the 50MB k16/vm16 stream (old k_segments
// dropped). cast16+castw merged into one launch. Rest identical to R16 (307us).

typedef float  f32x4  __attribute__((ext_vector_type(4)));
typedef _Float16 half8 __attribute__((ext_vector_type(8)));
typedef _Float16 half4 __attribute__((ext_vector_type(4)));

#define DEV __device__ __forceinline__
#define MFMA16(a, b, c) __builtin_amdgcn_mfma_f32_16x16x32_f16((a), (b), (c), 0, 0, 0)
#define GLOAD16(gp, lp)                                                  \
  __builtin_amdgcn_global_load_lds(                                      \
      (const __attribute__((address_space(1))) unsigned int*)(gp),       \
      (__attribute__((address_space(3))) unsigned int*)(lp), 16, 0, 0)

// ---------------- prep: all f32 -> fp16 casts in one launch ----------------
// x: 3145728 x4-units; then Wqkv 442368, Wv 65536, Wproj 147456.
__global__ __launch_bounds__(256) void k_castall(
    const float* __restrict__ x, const float* __restrict__ Wqkv,
    const float* __restrict__ Wv, const float* __restrict__ Wproj,
    _Float16* __restrict__ x16, _Float16* __restrict__ wq,
    _Float16* __restrict__ wv, _Float16* __restrict__ wp) {
  int i = blockIdx.x * 256 + threadIdx.x;
  const float* src;
  _Float16* dst;
  int idx = i;
  if (idx < 3145728) { src = x; dst = x16; }
  else if (idx < 3145728 + 442368) { src = Wqkv; dst = wq; idx -= 3145728; }
  else if (idx < 3145728 + 442368 + 65536) { src = Wv; dst = wv; idx -= 3145728 + 442368; }
  else if (idx < 3145728 + 442368 + 65536 + 147456) { src = Wproj; dst = wp; idx -= 3145728 + 442368 + 65536; }
  else return;
  f32x4 v = ((const f32x4*)src)[idx];
  half4 o;
#pragma unroll
  for (int c = 0; c < 4; ++c) o[c] = (_Float16)v[c];
  ((half4*)dst)[idx] = o;
}

// ---------------- qkv GEMM: C = A @ B^T, fp16, XCD-chunked 1D grid ----------------
__global__ __launch_bounds__(256, 3) void k_gemm_qkv(
    const _Float16* __restrict__ A16, const _Float16* __restrict__ B16,
    _Float16* __restrict__ qo, _Float16* __restrict__ ko, _Float16* __restrict__ v0o) {
  __shared__ _Float16 sA[128][64], sB[128][64];
  const int K = 768;
  int tid = threadIdx.x, lane = tid & 63, wave = tid >> 6;
  int l15 = lane & 15, g = lane >> 4;
  int wr = wave >> 1, wc = wave & 1;
  int wg = (blockIdx.x & 7) * 288 + (blockIdx.x >> 3);
  int n0 = (wg % 18) * 128, m0 = (wg / 18) * 128;
  f32x4 acc[4][4];
#pragma unroll
  for (int a = 0; a < 4; ++a)
#pragma unroll
    for (int b = 0; b < 4; ++b) acc[a][b] = f32x4{0.f, 0.f, 0.f, 0.f};
  int rsel = lane >> 3;
  int csel = (lane & 7) ^ rsel;
  for (int k0 = 0; k0 < K; k0 += 64) {
#pragma unroll
    for (int r = 0; r < 4; ++r) {
      int row = wave * 32 + r * 8 + rsel;
      GLOAD16(&A16[(size_t)(m0 + row) * K + k0 + csel * 8], &sA[wave * 32 + r * 8][0]);
      GLOAD16(&B16[(size_t)(n0 + row) * K + k0 + csel * 8], &sB[wave * 32 + r * 8][0]);
    }
    __syncthreads();
#pragma unroll
    for (int kk = 0; kk < 2; ++kk) {
      int kc = kk * 4 + g;
      int cc = ((kc ^ (l15 & 7)) << 3);
      half8 af[4], bf[4];
#pragma unroll
      for (int mf = 0; mf < 4; ++mf) af[mf] = *(const half8*)&sA[wr * 64 + mf * 16 + l15][cc];
#pragma unroll
      for (int nf = 0; nf < 4; ++nf) bf[nf] = *(const half8*)&sB[wc * 64 + nf * 16 + l15][cc];
#pragma unroll
      for (int mf = 0; mf < 4; ++mf)
#pragma unroll
        for (int nf = 0; nf < 4; ++nf)
          acc[mf][nf] = MFMA16(af[mf], bf[nf], acc[mf][nf]);
    }
    __syncthreads();
  }
  int sec = n0 / 768;
  int nb = n0 - sec * 768;
#pragma unroll
  for (int mf = 0; mf < 4; ++mf)
#pragma unroll
    for (int nf = 0; nf < 4; ++nf)
#pragma unroll
      for (int r = 0; r < 4; ++r) {
        int m = m0 + wr * 64 + mf * 16 + (g << 2) + r;
        int n = nb + wc * 64 + nf * 16 + l15;
        int b = m >> 11, t = m & 2047;
        int h = n >> 6, d = n & 63;
        size_t idx = (((size_t)b * 12 + h) * 2048 + t) * 64 + d;
        _Float16 val = (_Float16)acc[mf][nf][r];
        if (sec == 0) qo[idx] = val;
        else if (sec == 1) ko[idx] = val;
        else v0o[idx] = val;
      }
}

// ---------------- v = (k (x) v0) @ Wv^T + bv  (fp16, LDS-shared B tiles) ----------------
__global__ __launch_bounds__(256, 3) void k_veins(
    const _Float16* __restrict__ kh, const _Float16* __restrict__ v0g,
    const _Float16* __restrict__ Wvh, const float* __restrict__ bv,
    _Float16* __restrict__ vout) {
  __shared__ _Float16 ks[256][72];
  __shared__ _Float16 sB[2][64][64];
  int tid = threadIdx.x, lane = tid & 63, wave = tid >> 6;
  int l15 = lane & 15, g = lane >> 4, g8 = g << 3;
  size_t row0 = (size_t)blockIdx.x * 256;

  int srow_lo = wave * 8 + (lane >> 3);
  int scsrc = (lane & 7) ^ (lane >> 3);
  auto STAGE = [&](int b, int i) {
#pragma unroll
    for (int h = 0; h < 2; ++h) {
      GLOAD16(&Wvh[(size_t)(h * 32 + srow_lo) * 4096 + i * 64 + (scsrc << 3)],
              ((_Float16*)sB) + (size_t)b * 4096 + (h * 256 + wave * 64) * 8);
    }
  };

#pragma unroll
  for (int r = 0; r < 8; ++r) {
    int row = (tid >> 3) + r * 32;
    int c8 = (tid & 7) << 3;
    *(half8*)&ks[row][c8] = *(const half8*)&kh[(row0 + row) * 64 + c8];
  }
  half8 v0r[4][2];
#pragma unroll
  for (int mf = 0; mf < 4; ++mf) {
    size_t rb = (row0 + wave * 64 + mf * 16 + l15) * 64;
#pragma unroll
    for (int kk = 0; kk < 2; ++kk)
      v0r[mf][kk] = *(const half8*)&v0g[rb + kk * 32 + g8];
  }
  f32x4 acc[4][4];
#pragma unroll
  for (int a = 0; a < 4; ++a)
#pragma unroll
    for (int b = 0; b < 4; ++b) acc[a][b] = f32x4{0.f, 0.f, 0.f, 0.f};

  STAGE(0, 0);
  __syncthreads();
  int r0 = wave * 64 + l15;
  for (int i8 = 0; i8 < 8; ++i8) {
    half8 kr0 = *(const half8*)&ks[r0][i8 * 8];
    half8 kr1 = *(const half8*)&ks[r0 + 16][i8 * 8];
    half8 kr2 = *(const half8*)&ks[r0 + 32][i8 * 8];
    half8 kr3 = *(const half8*)&ks[r0 + 48][i8 * 8];
#pragma unroll
    for (int ii = 0; ii < 8; ++ii) {
      int i = i8 * 8 + ii;
      int cur = i & 1;
      if (i < 63) STAGE(cur ^ 1, i + 1);
      half8 b0[4], b1[4];
#pragma unroll
      for (int nf = 0; nf < 4; ++nf) {
        b0[nf] = *(const half8*)&sB[cur][nf * 16 + l15][((g ^ (l15 & 7)) << 3)];
        b1[nf] = *(const half8*)&sB[cur][nf * 16 + l15][(((4 + g) ^ (l15 & 7)) << 3)];
      }
      _Float16 kv0 = kr0[ii], kv1 = kr1[ii], kv2 = kr2[ii], kv3 = kr3[ii];
      {
        half8 a0 = v0r[0][0] * kv0, a1 = v0r[1][0] * kv1;
        half8 a2 = v0r[2][0] * kv2, a3 = v0r[3][0] * kv3;
#pragma unroll
        for (int nf = 0; nf < 4; ++nf) {
          acc[0][nf] = MFMA16(a0, b0[nf], acc[0][nf]);
          acc[1][nf] = MFMA16(a1, b0[nf], acc[1][nf]);
          acc[2][nf] = MFMA16(a2, b0[nf], acc[2][nf]);
          acc[3][nf] = MFMA16(a3, b0[nf], acc[3][nf]);
        }
      }
      {
        half8 a0 = v0r[0][1] * kv0, a1 = v0r[1][1] * kv1;
        half8 a2 = v0r[2][1] * kv2, a3 = v0r[3][1] * kv3;
#pragma unroll
        for (int nf = 0; nf < 4; ++nf) {
          acc[0][nf] = MFMA16(a0, b1[nf], acc[0][nf]);
          acc[1][nf] = MFMA16(a1, b1[nf], acc[1][nf]);
          acc[2][nf] = MFMA16(a2, b1[nf], acc[2][nf]);
          acc[3][nf] = MFMA16(a3, b1[nf], acc[3][nf]);
        }
      }
      __syncthreads();
    }
  }
#pragma unroll
  for (int mf = 0; mf < 4; ++mf)
#pragma unroll
    for (int nf = 0; nf < 4; ++nf) {
      int e = (nf << 4) + l15;
      float bve = bv[e];
#pragma unroll
      for (int r = 0; r < 4; ++r) {
        int row = wave * 64 + mf * 16 + (g << 2) + r;
        vout[(row0 + row) * 64 + e] = (_Float16)(acc[mf][nf][r] + bve);
      }
    }
}

// ---------------- tail prefixes + level-0 sums (bh XCD-chunked) ----------------
__global__ __launch_bounds__(256) void k_tails(
    const _Float16* __restrict__ km, const _Float16* __restrict__ vm,
    _Float16* __restrict__ tKg, _Float16* __restrict__ tVt,
    float* __restrict__ L0K, float* __restrict__ L0V) {
  int B = blockIdx.x;                       // 768 blocks
  int bh = (B & 7) * 12 + (B >> 6);         // XCD B%8 -> bh chunk [12c,12c+12)
  int seg16 = ((B >> 3) & 7) * 16;          // 8 sub-blocks per bh
  int wave = threadIdx.x >> 6, lane = threadIdx.x & 63;
  for (int task = wave; task < 32; task += 4) {
    int blk = seg16 + (task >> 1);
    size_t base = ((size_t)bh * 2048 + blk * 16) * 64 + lane;
    if (!(task & 1)) {  // K prefix, [t][d] layout; final = level-0 segment sum
      float ka = 0.f;
      _Float16* o = tKg + (((size_t)bh * 128 + blk) * 16) * 64 + lane;
#pragma unroll
      for (int t = 0; t < 16; ++t) {
        ka += (float)km[base + t * 64];
        o[t * 64] = (_Float16)ka;
      }
      L0K[((size_t)bh * 128 + blk) * 64 + lane] = ka;
    } else {            // V prefix, [e][t] layout; final = level-0 segment sum
      float va = 0.f;
      half8 lo = {}, hi = {};
#pragma unroll
      for (int t = 0; t < 8; ++t) {
        va += (float)vm[base + t * 64];
        lo[t] = (_Float16)va;
      }
#pragma unroll
      for (int t = 0; t < 8; ++t) {
        va += (float)vm[base + (t + 8) * 64];
        hi[t] = (_Float16)va;
      }
      _Float16* o = tVt + (((size_t)bh * 128 + blk) * 64 + lane) * 16;
      ((half8*)o)[0] = lo;
      ((half8*)o)[1] = hi;
      L0V[((size_t)bh * 128 + blk) * 64 + lane] = va;
    }
  }
}

// ---------------- hierarchy from level-0 sums (6MB instead of 50MB) ----------------
__global__ __launch_bounds__(256) void k_hier(
    const float* __restrict__ L0K, const float* __restrict__ L0V,
    _Float16* __restrict__ Ks, _Float16* __restrict__ Vt) {
  __shared__ float Ls[255][64];
  int s = blockIdx.x;
  int bh = (s & 7) * 12 + (s >> 3);   // 96 blocks, matches k_tails' XCD chunking
  int tid = threadIdx.x;
  // ---- K ----
  for (int task = tid; task < 8192; task += 256)
    Ls[task >> 6][task & 63] = L0K[(size_t)bh * 8192 + task];
  __syncthreads();
  {
    int bprev = 0, bcur = 128, cnt = 64;
    for (int lev = 1; lev < 8; ++lev) {
      for (int task = tid; task < cnt * 64; task += 256) {
        int i = task >> 6, d = task & 63;
        Ls[bcur + i][d] = Ls[bprev + 2 * i][d] + Ls[bprev + 2 * i + 1][d];
      }
      __syncthreads();
      bprev = bcur; bcur += cnt; cnt >>= 1;
    }
  }
  for (int task = tid; task < 16384; task += 256) {
    int seg = task >> 6;
    float v = (seg < 255) ? Ls[seg][task & 63] : 0.f;
    Ks[(size_t)bh * 16384 + task] = (_Float16)v;
  }
  __syncthreads();
  // ---- V ----
  for (int task = tid; task < 8192; task += 256)
    Ls[task >> 6][task & 63] = L0V[(size_t)bh * 8192 + task];
  __syncthreads();
  {
    int bprev = 0, bcur = 128, cnt = 64;
    for (int lev = 1; lev < 8; ++lev) {
      for (int task = tid; task < cnt * 64; task += 256) {
        int i = task >> 6, d = task & 63;
        Ls[bcur + i][d] = Ls[bprev + 2 * i][d] + Ls[bprev + 2 * i + 1][d];
      }
      __syncthreads();
      bprev = bcur; bcur += cnt; cnt >>= 1;
    }
  }
  for (int task = tid; task < 16384; task += 256) {
    int d = task >> 8, seg = task & 255;
    float v = (seg < 255) ? Ls[seg][d] : 0.f;
    Vt[(size_t)bh * 16384 + task] = (_Float16)v;
  }
}

// ---------------- MFMA attention (fp16): DMA-staged Ks/Vt chunks, 3 blocks/CU ----------------
__global__ __launch_bounds__(256, 3) void k_attn2(
    const _Float16* __restrict__ qm,
    const _Float16* __restrict__ tKg, const _Float16* __restrict__ tVt,
    const _Float16* __restrict__ Ks, const _Float16* __restrict__ Vt,
    _Float16* __restrict__ outp) {
  __shared__ __align__(16) _Float16 P[4][16][280];     // 35840 B
  __shared__ __align__(16) _Float16 sKs[2][32][64];    //  8192 B
  __shared__ __align__(16) _Float16 sVt[2][64][32];    //  8192 B  -> 52224 total
  int tid = threadIdx.x, lane = tid & 63, wave = tid >> 6;
  int orig = blockIdx.y * 32 + blockIdx.x;
  int wg = (orig & 7) * 384 + (orig >> 3);
  int tile = wg & 31, bh = wg >> 5;
  int t0 = tile * 64, tw0 = t0 + wave * 16;
  int blkw = tile * 4 + wave;
  size_t bh2048 = (size_t)bh * 2048;
  int l15 = lane & 15, g = lane >> 4, g8 = g << 3;

  const _Float16* KsB = Ks + (size_t)bh * 16384;
  const _Float16* VB = Vt + (size_t)bh * 16384;

  auto STAGE_K = [&](int buf, int c) {
    GLOAD16(KsB + (size_t)(c * 32 + wave * 8 + (lane >> 3)) * 64 +
                (((lane & 7) ^ ((lane >> 3) & 7)) << 3),
            &sKs[buf][wave * 8][0]);
  };
  auto STAGE_VT = [&](int buf, int c) {
    GLOAD16(VB + (size_t)(wave * 16 + (lane >> 2)) * 256 + c * 32 +
                (((lane & 3) ^ ((lane >> 2) & 3)) << 3),
            &sVt[buf][wave * 16][0]);
  };

  half8 qf0, qf1, t0f, t1f;
  {
    const _Float16* qp = qm + (bh2048 + tw0 + l15) * 64 + g8;
    qf0 = *(const half8*)qp;
    qf1 = *(const half8*)(qp + 32);
    const _Float16* tp = tKg + (((size_t)bh * 128 + blkw) * 16 + l15) * 64 + g8;
    t0f = *(const half8*)tp;
    t1f = *(const half8*)(tp + 32);
  }
  STAGE_K(0, 0);

  unsigned mA = 0, mE = 0;
#pragma unroll
  for (int nf = 0; nf < 16; ++nf) {
    int seg = nf * 16 + l15;
    if (seg < 255) {
      int m = 256 - seg;
      int cl = 32 - __clz(m - 1);
      int lev = 8 - cl;
      int rdx = (seg - (256 - (256 >> lev)) + 1) * (16 << lev) - 1;
      if (rdx < tw0) mA |= 1u << nf;
      else if (rdx == tw0 + 15) mE |= 1u << nf;
    }
  }

  f32x4 acc[17];
#pragma unroll
  for (int i = 0; i < 17; ++i) acc[i] = f32x4{0.f, 0.f, 0.f, 0.f};

  // ---- QK^T over 8 staged chunks ----
  __syncthreads();
#pragma unroll
  for (int c = 0; c < 8; ++c) {
    if (c < 7) STAGE_K((c + 1) & 1, c + 1);
    int bs = c & 1;
#pragma unroll
    for (int p = 0; p < 2; ++p) {
      int row = p * 16 + l15;
      half8 b0 = *(const half8*)&sKs[bs][row][(g ^ (l15 & 7)) << 3];
      half8 b1 = *(const half8*)&sKs[bs][row][((g + 4) ^ (l15 & 7)) << 3];
      acc[2 * c + p] = MFMA16(qf0, b0, acc[2 * c + p]);
      acc[2 * c + p] = MFMA16(qf1, b1, acc[2 * c + p]);
    }
    __syncthreads();
  }
  acc[16] = MFMA16(qf0, t0f, acc[16]);
  acc[16] = MFMA16(qf1, t1f, acc[16]);

  STAGE_VT(0, 0);
  STAGE_VT(1, 1);

  // ---- softmax (f32, exp2 domain, deferred normalization) ----
  const float c2 = 0.125f * 1.44269504f;
  float mx[4], sm[4], et[4];
#pragma unroll
  for (int r = 0; r < 4; ++r) {
    int tr = g * 4 + r;
    mx[r] = (l15 == tr) ? acc[16][r] * c2 : -3.0e38f;
  }
#pragma unroll
  for (int nf = 0; nf < 16; ++nf) {
    bool bA = (mA >> nf) & 1, bE = (mE >> nf) & 1;
#pragma unroll
    for (int r = 0; r < 4; ++r) {
      bool u = bA || (bE && g == 3 && r == 3);
      if (u) mx[r] = fmaxf(mx[r], acc[nf][r] * c2);
    }
  }
#pragma unroll
  for (int off = 1; off < 16; off <<= 1)
#pragma unroll
    for (int r = 0; r < 4; ++r) mx[r] = fmaxf(mx[r], __shfl_xor(mx[r], off));
#pragma unroll
  for (int r = 0; r < 4; ++r) {
    int tr = g * 4 + r;
    et[r] = (l15 == tr) ? exp2f(acc[16][r] * c2 - mx[r]) : 0.f;
    sm[r] = et[r];
  }
#pragma unroll
  for (int nf = 0; nf < 16; ++nf) {
    bool bA = (mA >> nf) & 1, bE = (mE >> nf) & 1;
#pragma unroll
    for (int r = 0; r < 4; ++r) {
      bool u = bA || (bE && g == 3 && r == 3);
      float e = u ? exp2f(acc[nf][r] * c2 - mx[r]) : 0.f;
      acc[nf][r] = e;
      sm[r] += e;
    }
  }
#pragma unroll
  for (int off = 1; off < 16; off <<= 1)
#pragma unroll
    for (int r = 0; r < 4; ++r) sm[r] += __shfl_xor(sm[r], off);
  float inv[4];
#pragma unroll
  for (int r = 0; r < 4; ++r) inv[r] = 1.f / sm[r];

  // ---- P writes (raw exp values; normalization deferred) ----
  {
    half4 z4 = {};
    *(half4*)&P[wave][lane >> 2][256 + (lane & 3) * 4] = z4;
  }
#pragma unroll
  for (int nf = 0; nf < 16; ++nf)
#pragma unroll
    for (int r = 0; r < 4; ++r)
      P[wave][g * 4 + r][nf * 16 + l15] = (_Float16)acc[nf][r];
#pragma unroll
  for (int r = 0; r < 4; ++r)
    if (l15 == g * 4 + r) P[wave][l15][256 + l15] = (_Float16)et[r];

  // ---- PV over 8 staged chunks ----
  f32x4 oa[4];
#pragma unroll
  for (int i = 0; i < 4; ++i) oa[i] = f32x4{0.f, 0.f, 0.f, 0.f};
  __syncthreads();
#pragma unroll
  for (int c = 0; c < 8; ++c) {
    int bs = c & 1;
    half8 pa = *(const half8*)&P[wave][l15][c * 32 + g8];
#pragma unroll
    for (int n2 = 0; n2 < 4; ++n2) {
      half8 vb = *(const half8*)&sVt[bs][n2 * 16 + l15][(g ^ (l15 & 3)) << 3];
      oa[n2] = MFMA16(pa, vb, oa[n2]);
    }
    __syncthreads();
    if (c < 6) STAGE_VT(bs, c + 2);
  }
  {  // tail k-step
    half8 pa = *(const half8*)&P[wave][l15][256 + (g & 1) * 8];
    const _Float16* tvb = tVt + ((size_t)bh * 128 + blkw) * 1024;
#pragma unroll
    for (int n2 = 0; n2 < 4; ++n2) {
      half8 vt = {};
      if (g < 2)
        vt = *(const half8*)(tvb + (size_t)(n2 * 16 + l15) * 16 + g8);
      oa[n2] = MFMA16(pa, vt, oa[n2]);
    }
  }
  // ---- output (normalize here) ----
  int b = bh / 12, h = bh - b * 12;
  size_t obase = ((size_t)b * 2048 + tw0) * 768 + h * 64;
#pragma unroll
  for (int n2 = 0; n2 < 4; ++n2)
#pragma unroll
    for (int r = 0; r < 4; ++r)
      outp[obase + (size_t)(g * 4 + r) * 768 + n2 * 16 + l15] = (_Float16)(oa[n2][r] * inv[r]);
}

// ---------------- proj GEMM: d_out = out_pre @ Wproj^T (fp16, XCD-chunked) ----------------
__global__ __launch_bounds__(256, 3) void k_gemm_proj(
    const _Float16* __restrict__ A16, const _Float16* __restrict__ B16,
    float* __restrict__ C) {
  __shared__ _Float16 sA[128][64], sB[128][64];
  const int K = 768;
  int tid = threadIdx.x, lane = tid & 63, wave = tid >> 6;
  int l15 = lane & 15, g = lane >> 4;
  int wr = wave >> 1, wc = wave & 1;
  int wg = (blockIdx.x & 7) * 96 + (blockIdx.x >> 3);
  int n0 = (wg % 6) * 128, m0 = (wg / 6) * 128;
  f32x4 acc[4][4];
#pragma unroll
  for (int a = 0; a < 4; ++a)
#pragma unroll
    for (int b = 0; b < 4; ++b) acc[a][b] = f32x4{0.f, 0.f, 0.f, 0.f};
  int rsel = lane >> 3;
  int csel = (lane & 7) ^ rsel;
  for (int k0 = 0; k0 < K; k0 += 64) {
#pragma unroll
    for (int r = 0; r < 4; ++r) {
      int row = wave * 32 + r * 8 + rsel;
      GLOAD16(&A16[(size_t)(m0 + row) * K + k0 + csel * 8], &sA[wave * 32 + r * 8][0]);
      GLOAD16(&B16[(size_t)(n0 + row) * K + k0 + csel * 8], &sB[wave * 32 + r * 8][0]);
    }
    __syncthreads();
#pragma unroll
    for (int kk = 0; kk < 2; ++kk) {
      int kc = kk * 4 + g;
      int cc = ((kc ^ (l15 & 7)) << 3);
      half8 af[4], bf[4];
#pragma unroll
      for (int mf = 0; mf < 4; ++mf) af[mf] = *(const half8*)&sA[wr * 64 + mf * 16 + l15][cc];
#pragma unroll
      for (int nf = 0; nf < 4; ++nf) bf[nf] = *(const half8*)&sB[wc * 64 + nf * 16 + l15][cc];
#pragma unroll
      for (int mf = 0; mf < 4; ++mf)
#pragma unroll
        for (int nf = 0; nf < 4; ++nf)
          acc[mf][nf] = MFMA16(af[mf], bf[nf], acc[mf][nf]);
    }
    __syncthreads();
  }
#pragma unroll
  for (int mf = 0; mf < 4; ++mf)
#pragma unroll
    for (int nf = 0; nf < 4; ++nf)
#pragma unroll
      for (int r = 0; r < 4; ++r) {
        int m = m0 + wr * 64 + mf * 16 + (g << 2) + r;
        int n = n0 + wc * 64 + nf * 16 + l15;
        C[(size_t)m * 768 + n] = acc[mf][nf][r];
      }
}

// ---------------- host launch ----------------
extern "C" void kernel_launch(void* const* d_in, const int* in_sizes, int n_in,
                              void* d_out, int out_size, void* d_ws, size_t ws_size,
                              hipStream_t stream) {
  const float* x = (const float*)d_in[0];
  const float* Wqkv = (const float*)d_in[1];
  const float* Wproj = (const float*)d_in[2];
  const float* Wv = (const float*)d_in[3];
  const float* bv = (const float*)d_in[4];
  float* out = (float*)d_out;
  char* ws = (char*)d_ws;
  size_t off = 0;
  auto alloc = [&](size_t bytes) -> void* {
    void* p = (void*)(ws + off);
    off += (bytes + 255) & ~(size_t)255;
    return p;
  };
  _Float16* x16  = (_Float16*)alloc(12582912ull * 2);
  _Float16* wq16 = (_Float16*)alloc(1769472ull * 2);
  _Float16* wv16 = (_Float16*)alloc(262144ull * 2 + 8192);
  _Float16* wp16 = (_Float16*)alloc(589824ull * 2);
  _Float16* q16  = (_Float16*)alloc(12582912ull * 2);
  _Float16* k16  = (_Float16*)alloc(12582912ull * 2);
  _Float16* v016 = (_Float16*)alloc(12582912ull * 2);
  _Float16* vm16 = (_Float16*)alloc(12582912ull * 2);
  _Float16* Ks   = (_Float16*)alloc(1572864ull * 2);
  _Float16* Vt   = (_Float16*)alloc(1572864ull * 2);
  _Float16* tKg  = (_Float16*)alloc(12582912ull * 2);
  _Float16* tVt  = (_Float16*)alloc(12582912ull * 2);
  float*    L0K  = (float*)alloc(786432ull * 4);
  float*    L0V  = (float*)alloc(786432ull * 4);
  _Float16* outp = (_Float16*)alloc(12582912ull * 2);

  k_castall<<<dim3(14848), dim3(256), 0, stream>>>(x, Wqkv, Wv, Wproj, x16, wq16, wv16, wp16);
  k_gemm_qkv<<<dim3(2304), dim3(256), 0, stream>>>(x16, wq16, q16, k16, v016);
  k_veins<<<dim3(768), dim3(256), 0, stream>>>(k16, v016, wv16, bv, vm16);
  k_tails<<<dim3(768), dim3(256), 0, stream>>>(k16, vm16, tKg, tVt, L0K, L0V);
  k_hier<<<dim3(96), dim3(256), 0, stream>>>(L0K, L0V, Ks, Vt);
  k_attn2<<<dim3(32, 96), dim3(256), 0, stream>>>(q16, tKg, tVt, Ks, Vt, outp);
  k_gemm_proj<<<dim3(768), dim3(256), 0, stream>>>(outp, wp16, out);
}